// Round 1
// baseline (211.824 us; speedup 1.0000x reference)
//
#include <hip/hip_runtime.h>
#include <math.h>

// Problem constants
#define NVOX  32768     // 32^3 up-res voxels
#define CIN   64
#define COUT  32
#define KT    27
#define CIT   1728      // CIN*KT
#define PSP   5832      // 18^3 padded half-res spatial

// Workspace layout (float offsets)
#define WS_XT   0                 // fp16[5832][64] channel-last padded x
#define WS_WA   186624            // fp16[216][32][8] deform-W A-frags (K tap-major)
#define WS_WO   214272            // fp16[216][96][8] offset-W A-frags (M padded 81->96)
#define WS_STAT 297216            // [32] sum, [32] sumsq
#define WS_P    297280            // fp16[81][32768] offsets (m-major), 5.31 MB

typedef __attribute__((ext_vector_type(8))) _Float16 half8;
typedef __attribute__((ext_vector_type(2))) _Float16 half2v;
typedef __attribute__((ext_vector_type(4))) float floatx4;

static __device__ __forceinline__ unsigned dup16(float w) {
    unsigned short b = __builtin_bit_cast(unsigned short, (_Float16)w);
    return (unsigned)b * 0x10001u;
}
static __device__ __forceinline__ half2v u2h2(unsigned u) {
    return __builtin_bit_cast(half2v, u);
}
static __device__ __forceinline__ half8 pk8(half2v a, half2v b, half2v c, half2v d) {
    union { half8 v; half2v p[4]; } u;
    u.p[0] = a; u.p[1] = b; u.p[2] = c; u.p[3] = d;
    return u.v;
}

// ---------------------------------------------------------------------------
// Merged prep (UNCHANGED from previous round — verified):
//   blocks [0,92):    XT fill via LDS transpose
//   blocks [92,119):  pack wmat  -> WA
//   blocks [119,200): pack w_off -> WO
//   block  200:       zero stats
// ---------------------------------------------------------------------------
__global__ __launch_bounds__(256) void prep_all_kernel(
        const float* __restrict__ x, const float* __restrict__ w_off,
        const float* __restrict__ wmat, float* __restrict__ ws) {
    int b = blockIdx.x, t = threadIdx.x;
    if (b < 92) {
        __shared__ _Float16 tile[64][65];
        _Float16* xth = (_Float16*)(ws + WS_XT);
        int tq = t >> 6, lane = t & 63;
        int base = b * 64;
        int cell = base + lane;
        int qw = cell % 18, qh = (cell / 18) % 18, qd = cell / 324;
        bool interior = (cell < PSP) && qd >= 1 && qd <= 16 && qh >= 1 && qh <= 16
                        && qw >= 1 && qw <= 16;
        int xbase = interior ? (((qd - 1) * 16 + (qh - 1)) * 16 + (qw - 1)) : 0;
#pragma unroll
        for (int i = 0; i < 16; i++) {
            int c = tq * 16 + i;
            float v = interior ? x[c * 4096 + xbase] : 0.f;
            tile[lane][c] = (_Float16)v;
        }
        __syncthreads();
#pragma unroll
        for (int i = 0; i < 16; i++) {
            int s = tq * 16 + i;
            int cell2 = base + s;
            if (cell2 < PSP) xth[cell2 * 64 + lane] = tile[s][lane];
        }
    } else if (b < 119) {
        _Float16* wa = (_Float16*)(ws + WS_WA);
        int idx = (b - 92) * 256 + t;           // 0..6911  (kb, o)
        int kb = idx >> 5, o = idx & 31;
        half8 r;
#pragma unroll
        for (int j = 0; j < 8; j++) {
            int kk = kb * 8 + j;                // K index, tap-major
            int tap = kk >> 6, ci = kk & 63;
            r[j] = (_Float16)wmat[o * CIT + ci * 27 + tap];
        }
        *(half8*)(wa + idx * 8) = r;
    } else if (b < 200) {
        _Float16* wo = (_Float16*)(ws + WS_WO);
        int idx = (b - 119) * 256 + t;          // 0..20735 = kb*96 + m
        int kb = idx / 96, m = idx % 96;
        half8 r;
#pragma unroll
        for (int j = 0; j < 8; j++) {
            int kk = kb * 8 + j;
            int tap = kk >> 6, ci = kk & 63;
            float v = (m < 81) ? w_off[(m * 64 + ci) * 27 + tap] : 0.f;
            r[j] = (_Float16)v;
        }
        *(half8*)(wo + idx * 8) = r;
    } else {
        if (t < 64) ws[WS_STAT + t] = 0.f;
    }
}

// ---------------------------------------------------------------------------
// Kernel A: offset GEMM. M=96(81), K=1728, N-tile=32 (one full w-row).
// Per-tap A chunk (8 kb x 96 x 16B = 12 KB) staged in LDS, double-buffered,
// 1 barrier per tap. B-fragments read register-direct from XT (im2col addr).
// Waves: (nsub = voxel half, kh = K-step within tap). 1024 blocks = 4/CU.
// ---------------------------------------------------------------------------
__global__ __launch_bounds__(256, 4) void offset_kernel(
        const float* __restrict__ b_off, float* ws) {
    __shared__ __align__(16) _Float16 abuf[2 * 6144];   // 2 x 12288 B
    int tid = threadIdx.x, wave = tid >> 6, lane = tid & 63;
    int nsub = wave & 1, kh = wave >> 1;
    int col = lane & 15, quad = lane >> 4;
    int pbase = blockIdx.x * 32;
    int d = blockIdx.x >> 5, h = blockIdx.x & 31;
    int vox = nsub * 16 + col;                  // w coordinate
    const char* xtb = (const char*)(ws + WS_XT);
    const int4* wsrc = (const int4*)(ws + WS_WO);   // half8 == 16B units
    _Float16* Pw = (_Float16*)(ws + WS_P);
    int4* ab4 = (int4*)abuf;

    // prologue: stage tap 0, preload tap 1 into regs
    int4 ra0 = wsrc[tid], ra1 = wsrc[256 + tid], ra2 = wsrc[512 + tid];
    ab4[tid] = ra0; ab4[256 + tid] = ra1; ab4[512 + tid] = ra2;
    ra0 = wsrc[768 + tid]; ra1 = wsrc[768 + 256 + tid]; ra2 = wsrc[768 + 512 + tid];
    __syncthreads();

    floatx4 acc[6];
#pragma unroll
    for (int mt = 0; mt < 6; mt++) acc[mt] = (floatx4){0.f, 0.f, 0.f, 0.f};

    int fb = (kh * 4 + quad) * 768 + col * 8;   // half-offset of this lane's frags

#pragma unroll 1
    for (int tap = 0; tap < 27; tap++) {
        if (tap < 26) {                          // write tap+1 into other buffer
            int4* dst = ab4 + ((tap + 1) & 1) * 768;
            dst[tid] = ra0; dst[256 + tid] = ra1; dst[512 + tid] = ra2;
        }
        if (tap < 25) {                          // preload tap+2
            const int4* s = wsrc + (tap + 2) * 768;
            ra0 = s[tid]; ra1 = s[256 + tid]; ra2 = s[512 + tid];
        }
        int kd = tap / 9, r9 = tap - kd * 9, kh2 = r9 / 3, kw2 = r9 - kh2 * 3;
        int rd = ((d + kd - 1) >> 1) + 1;
        int rh = ((h + kh2 - 1) >> 1) + 1;
        int rw = ((vox + kw2 - 1) >> 1) + 1;
        int cell = (rd * 18 + rh) * 18 + rw;
        int4 bx = *(const int4*)(xtb + cell * 128 + kh * 64 + quad * 16);
        half8 bfrag = __builtin_bit_cast(half8, bx);
        const _Float16* abh = abuf + (tap & 1) * 6144;
#pragma unroll
        for (int mt = 0; mt < 6; mt++) {
            half8 af = *(const half8*)(abh + fb + mt * 128);
            acc[mt] = __builtin_amdgcn_mfma_f32_16x16x32_f16(af, bfrag, acc[mt], 0, 0, 0);
        }
        __syncthreads();
    }

    // kh reduce through LDS (abuf is free after loop-end barrier)
    float* red = (float*)abuf;                   // [(nsub*96+m)*17 + col], 13 KB
    if (kh == 1) {
#pragma unroll
        for (int mt = 0; mt < 6; mt++)
#pragma unroll
            for (int r = 0; r < 4; r++)
                red[(nsub * 96 + mt * 16 + quad * 4 + r) * 17 + col] = acc[mt][r];
    }
    __syncthreads();
    if (kh == 0) {
#pragma unroll
        for (int mt = 0; mt < 6; mt++)
#pragma unroll
            for (int r = 0; r < 4; r++) {
                int m = mt * 16 + quad * 4 + r;
                if (m < 81) {
                    float v = acc[mt][r] + red[(nsub * 96 + m) * 17 + col] + b_off[m];
                    Pw[m * NVOX + pbase + nsub * 16 + col] = (_Float16)v;
                }
            }
    }
}

// ---------------------------------------------------------------------------
// Kernel B: deformable sample + GEMM + BN stats. Register-direct gather:
// lane (col,quad) owns voxel col and channel slice quad*8 -> the 8-corner
// trilinear sum IS the MFMA B-fragment. No LDS staging, no barriers in the
// main loop. Waves: (nsub = voxel half, kt = tap half 14/13). 1024 blocks.
// ---------------------------------------------------------------------------
#define GATH(Ax, Wx) do { \
    int4 x0_ = *(const int4*)(xtb + (Ax) + sub); \
    int4 x1_ = *(const int4*)(xtb + (Ax) + sub + 64); \
    s00 += (Wx) * u2h2((unsigned)x0_.x); s01 += (Wx) * u2h2((unsigned)x0_.y); \
    s02 += (Wx) * u2h2((unsigned)x0_.z); s03 += (Wx) * u2h2((unsigned)x0_.w); \
    s10 += (Wx) * u2h2((unsigned)x1_.x); s11 += (Wx) * u2h2((unsigned)x1_.y); \
    s12 += (Wx) * u2h2((unsigned)x1_.z); s13 += (Wx) * u2h2((unsigned)x1_.w); \
} while (0)

__global__ __launch_bounds__(256, 4) void deform_kernel(
        const float* __restrict__ bias, float* ws, float* __restrict__ out) {
    __shared__ float pbuf[2][2][16][17];         // [nsub][mt][q4r][col], 4.3 KB
    __shared__ float rsum[COUT], rsq[COUT];
    int tid = threadIdx.x, wave = tid >> 6, lane = tid & 63;
    int nsub = wave & 1, kt = wave >> 1;
    int col = lane & 15, quad = lane >> 4;
    int pbase = blockIdx.x * 32;
    int d = blockIdx.x >> 5, h = blockIdx.x & 31;
    int vox = nsub * 16 + col;                   // w coordinate
    int gvox = pbase + vox;
    const char* xtb = (const char*)(ws + WS_XT);
    const half8* wa8 = (const half8*)(ws + WS_WA);
    const _Float16* P = (const _Float16*)(ws + WS_P);
    float* gstat = ws + WS_STAT;

    if (tid < COUT) { rsum[tid] = 0.f; rsq[tid] = 0.f; }

    floatx4 acc0 = {0.f, 0.f, 0.f, 0.f}, acc1 = {0.f, 0.f, 0.f, 0.f};
    int tbeg = kt ? 14 : 0, tend = kt ? 27 : 14;
    int sub = quad * 16;                         // byte offset of channel slice

#pragma unroll 1
    for (int tap = tbeg; tap < tend; tap++) {
        int kd = tap / 9, r9 = tap - kd * 9, kh2 = r9 / 3, kw2 = r9 - kh2 * 3;
        float od = (float)P[(3 * tap + 0) * NVOX + gvox];
        float oh = (float)P[(3 * tap + 1) * NVOX + gvox];
        float ow = (float)P[(3 * tap + 2) * NVOX + gvox];
        float pdc = (float)(d + kd - 1) + od;
        float phc = (float)(h + kh2 - 1) + oh;
        float pwc = (float)(vox + kw2 - 1) + ow;
        float fd0 = floorf(pdc), fh0 = floorf(phc), fw0 = floorf(pwc);
        float fd = pdc - fd0, fh = phc - fh0, fw = pwc - fw0;
        int id = (int)fd0, ih = (int)fh0, iw = (int)fw0;
        // corner bases in BYTES (cell * 128)
        int rd0 = ((min(max(id,     -2), 33) >> 1) + 1) * (324 * 128);
        int rd1 = ((min(max(id + 1, -2), 33) >> 1) + 1) * (324 * 128);
        int rh0 = ((min(max(ih,     -2), 33) >> 1) + 1) * (18 * 128);
        int rh1 = ((min(max(ih + 1, -2), 33) >> 1) + 1) * (18 * 128);
        int rw0 = ((min(max(iw,     -2), 33) >> 1) + 1) * 128;
        int rw1 = ((min(max(iw + 1, -2), 33) >> 1) + 1) * 128;
        int A0 = rd0 + rh0 + rw0, A1 = rd0 + rh0 + rw1;
        int A2 = rd0 + rh1 + rw0, A3 = rd0 + rh1 + rw1;
        int A4 = rd1 + rh0 + rw0, A5 = rd1 + rh0 + rw1;
        int A6 = rd1 + rh1 + rw0, A7 = rd1 + rh1 + rw1;
        float gd = 1.f - fd, gh = 1.f - fh, gw = 1.f - fw;
        half2v W0 = u2h2(dup16(gd * gh * gw)), W1 = u2h2(dup16(gd * gh * fw));
        half2v W2 = u2h2(dup16(gd * fh * gw)), W3 = u2h2(dup16(gd * fh * fw));
        half2v W4 = u2h2(dup16(fd * gh * gw)), W5 = u2h2(dup16(fd * gh * fw));
        half2v W6 = u2h2(dup16(fd * fh * gw)), W7 = u2h2(dup16(fd * fh * fw));

        half2v s00 = {0, 0}, s01 = {0, 0}, s02 = {0, 0}, s03 = {0, 0};
        half2v s10 = {0, 0}, s11 = {0, 0}, s12 = {0, 0}, s13 = {0, 0};
        GATH(A0, W0); GATH(A1, W1); GATH(A2, W2); GATH(A3, W3);
        GATH(A4, W4); GATH(A5, W5); GATH(A6, W6); GATH(A7, W7);
        half8 bf0 = pk8(s00, s01, s02, s03);     // k = tap*64 +  0 + quad*8 ..
        half8 bf1 = pk8(s10, s11, s12, s13);     // k = tap*64 + 32 + quad*8 ..

        int kb = tap * 8 + quad;
        half8 a00 = wa8[kb * 32 + col];
        half8 a01 = wa8[kb * 32 + 16 + col];
        half8 a10 = wa8[(kb + 4) * 32 + col];
        half8 a11 = wa8[(kb + 4) * 32 + 16 + col];
        acc0 = __builtin_amdgcn_mfma_f32_16x16x32_f16(a00, bf0, acc0, 0, 0, 0);
        acc1 = __builtin_amdgcn_mfma_f32_16x16x32_f16(a01, bf0, acc1, 0, 0, 0);
        acc0 = __builtin_amdgcn_mfma_f32_16x16x32_f16(a10, bf1, acc0, 0, 0, 0);
        acc1 = __builtin_amdgcn_mfma_f32_16x16x32_f16(a11, bf1, acc1, 0, 0, 0);
    }
    __syncthreads();
    if (kt == 1) {
#pragma unroll
        for (int r = 0; r < 4; r++) {
            pbuf[nsub][0][quad * 4 + r][col] = acc0[r];
            pbuf[nsub][1][quad * 4 + r][col] = acc1[r];
        }
    }
    __syncthreads();
    if (kt == 0) {
#pragma unroll
        for (int r = 0; r < 4; r++) {
            int o0 = quad * 4 + r;
            float v0 = acc0[r] + pbuf[nsub][0][quad * 4 + r][col] + bias[o0];
            out[o0 * NVOX + gvox] = v0;
            atomicAdd(&rsum[o0], v0);
            atomicAdd(&rsq[o0], v0 * v0);
            int o1 = 16 + quad * 4 + r;
            float v1 = acc1[r] + pbuf[nsub][1][quad * 4 + r][col] + bias[o1];
            out[o1 * NVOX + gvox] = v1;
            atomicAdd(&rsum[o1], v1);
            atomicAdd(&rsq[o1], v1 * v1);
        }
    }
    __syncthreads();
    if (tid < COUT) {
        atomicAdd(&gstat[tid], rsum[tid]);
        atomicAdd(&gstat[COUT + tid], rsq[tid]);
    }
}

// ---------------------------------------------------------------------------
// BN finalize + ReLU, in-place on d_out (unchanged).
// ---------------------------------------------------------------------------
__global__ void bn_kernel(const float* __restrict__ ws,
                          const float* __restrict__ gamma,
                          const float* __restrict__ beta,
                          float* out) {
    int i = blockIdx.x * 256 + threadIdx.x;
    int o = i >> 15;
    const float* gstat = ws + WS_STAT;
    const float inv = 1.f / 32768.f;
    float mean = gstat[o] * inv;
    float var  = gstat[COUT + o] * inv - mean * mean;
    float sc   = rsqrtf(var + 1e-5f) * gamma[o];
    float v = (out[i] - mean) * sc + beta[o];
    out[i] = fmaxf(v, 0.f);
}

// ---------------------------------------------------------------------------
extern "C" void kernel_launch(void* const* d_in, const int* in_sizes, int n_in,
                              void* d_out, int out_size, void* d_ws, size_t ws_size,
                              hipStream_t stream) {
    const float* x     = (const float*)d_in[0];
    const float* w_off = (const float*)d_in[1];
    const float* b_off = (const float*)d_in[2];
    const float* wmat  = (const float*)d_in[3];
    const float* bias  = (const float*)d_in[4];
    const float* gamma = (const float*)d_in[5];
    const float* beta  = (const float*)d_in[6];
    float* ws  = (float*)d_ws;
    float* out = (float*)d_out;

    prep_all_kernel<<<201, 256, 0, stream>>>(x, w_off, wmat, ws);
    offset_kernel<<<1024, 256, 0, stream>>>(b_off, ws);
    deform_kernel<<<1024, 256, 0, stream>>>(bias, ws, out);
    bn_kernel<<<4096, 256, 0, stream>>>(ws, gamma, beta, out);
}

// Round 2
// 191.790 us; speedup vs baseline: 1.1045x; 1.1045x over previous
//
#include <hip/hip_runtime.h>
#include <math.h>

// Problem constants
#define NVOX  32768     // 32^3 up-res voxels
#define CIN   64
#define COUT  32
#define KT    27
#define CIT   1728      // CIN*KT
#define PSP   5832      // 18^3 padded half-res spatial

// Workspace layout (float offsets)
#define WS_XT   0                 // fp16[5832][64] channel-last padded x
#define WS_WA   186624            // fp16[216][32][8] deform-W A-frags (K tap-major)
#define WS_WO   214272            // fp16[216][96][8] offset-W A-frags (M padded 81->96)
#define WS_STAT 297216            // [32] sum, [32] sumsq
#define WS_P    297280            // fp16[81][32768] offsets (m-major), 5.31 MB

typedef __attribute__((ext_vector_type(8))) _Float16 half8;
typedef __attribute__((ext_vector_type(2))) _Float16 half2v;
typedef __attribute__((ext_vector_type(4))) float floatx4;

static __device__ __forceinline__ unsigned dup16(float w) {
    unsigned short b = __builtin_bit_cast(unsigned short, (_Float16)w);
    return (unsigned)b * 0x10001u;
}
static __device__ __forceinline__ half2v u2h2(unsigned u) {
    return __builtin_bit_cast(half2v, u);
}
static __device__ __forceinline__ half8 pk8(half2v a, half2v b, half2v c, half2v d) {
    union { half8 v; half2v p[4]; } u;
    u.p[0] = a; u.p[1] = b; u.p[2] = c; u.p[3] = d;
    return u.v;
}

// ---------------------------------------------------------------------------
// Merged prep (UNCHANGED — verified):
//   blocks [0,92):    XT fill via LDS transpose
//   blocks [92,119):  pack wmat  -> WA
//   blocks [119,200): pack w_off -> WO
//   block  200:       zero stats
// ---------------------------------------------------------------------------
__global__ __launch_bounds__(256) void prep_all_kernel(
        const float* __restrict__ x, const float* __restrict__ w_off,
        const float* __restrict__ wmat, float* __restrict__ ws) {
    int b = blockIdx.x, t = threadIdx.x;
    if (b < 92) {
        __shared__ _Float16 tile[64][65];
        _Float16* xth = (_Float16*)(ws + WS_XT);
        int tq = t >> 6, lane = t & 63;
        int base = b * 64;
        int cell = base + lane;
        int qw = cell % 18, qh = (cell / 18) % 18, qd = cell / 324;
        bool interior = (cell < PSP) && qd >= 1 && qd <= 16 && qh >= 1 && qh <= 16
                        && qw >= 1 && qw <= 16;
        int xbase = interior ? (((qd - 1) * 16 + (qh - 1)) * 16 + (qw - 1)) : 0;
#pragma unroll
        for (int i = 0; i < 16; i++) {
            int c = tq * 16 + i;
            float v = interior ? x[c * 4096 + xbase] : 0.f;
            tile[lane][c] = (_Float16)v;
        }
        __syncthreads();
#pragma unroll
        for (int i = 0; i < 16; i++) {
            int s = tq * 16 + i;
            int cell2 = base + s;
            if (cell2 < PSP) xth[cell2 * 64 + lane] = tile[s][lane];
        }
    } else if (b < 119) {
        _Float16* wa = (_Float16*)(ws + WS_WA);
        int idx = (b - 92) * 256 + t;           // 0..6911  (kb, o)
        int kb = idx >> 5, o = idx & 31;
        half8 r;
#pragma unroll
        for (int j = 0; j < 8; j++) {
            int kk = kb * 8 + j;                // K index, tap-major
            int tap = kk >> 6, ci = kk & 63;
            r[j] = (_Float16)wmat[o * CIT + ci * 27 + tap];
        }
        *(half8*)(wa + idx * 8) = r;
    } else if (b < 200) {
        _Float16* wo = (_Float16*)(ws + WS_WO);
        int idx = (b - 119) * 256 + t;          // 0..20735 = kb*96 + m
        int kb = idx / 96, m = idx % 96;
        half8 r;
#pragma unroll
        for (int j = 0; j < 8; j++) {
            int kk = kb * 8 + j;
            int tap = kk >> 6, ci = kk & 63;
            float v = (m < 81) ? w_off[(m * 64 + ci) * 27 + tap] : 0.f;
            r[j] = (_Float16)v;
        }
        *(half8*)(wo + idx * 8) = r;
    } else {
        if (t < 64) ws[WS_STAT + t] = 0.f;
    }
}

// ---------------------------------------------------------------------------
// Kernel A: offset GEMM (UNCHANGED from round 1). M=96(81), K=1728, N-tile=32.
// ---------------------------------------------------------------------------
__global__ __launch_bounds__(256, 4) void offset_kernel(
        const float* __restrict__ b_off, float* ws) {
    __shared__ __align__(16) _Float16 abuf[2 * 6144];   // 2 x 12288 B
    int tid = threadIdx.x, wave = tid >> 6, lane = tid & 63;
    int nsub = wave & 1, kh = wave >> 1;
    int col = lane & 15, quad = lane >> 4;
    int pbase = blockIdx.x * 32;
    int d = blockIdx.x >> 5, h = blockIdx.x & 31;
    int vox = nsub * 16 + col;                  // w coordinate
    const char* xtb = (const char*)(ws + WS_XT);
    const int4* wsrc = (const int4*)(ws + WS_WO);   // half8 == 16B units
    _Float16* Pw = (_Float16*)(ws + WS_P);
    int4* ab4 = (int4*)abuf;

    // prologue: stage tap 0, preload tap 1 into regs
    int4 ra0 = wsrc[tid], ra1 = wsrc[256 + tid], ra2 = wsrc[512 + tid];
    ab4[tid] = ra0; ab4[256 + tid] = ra1; ab4[512 + tid] = ra2;
    ra0 = wsrc[768 + tid]; ra1 = wsrc[768 + 256 + tid]; ra2 = wsrc[768 + 512 + tid];
    __syncthreads();

    floatx4 acc[6];
#pragma unroll
    for (int mt = 0; mt < 6; mt++) acc[mt] = (floatx4){0.f, 0.f, 0.f, 0.f};

    int fb = (kh * 4 + quad) * 768 + col * 8;   // half-offset of this lane's frags

#pragma unroll 1
    for (int tap = 0; tap < 27; tap++) {
        if (tap < 26) {                          // write tap+1 into other buffer
            int4* dst = ab4 + ((tap + 1) & 1) * 768;
            dst[tid] = ra0; dst[256 + tid] = ra1; dst[512 + tid] = ra2;
        }
        if (tap < 25) {                          // preload tap+2
            const int4* s = wsrc + (tap + 2) * 768;
            ra0 = s[tid]; ra1 = s[256 + tid]; ra2 = s[512 + tid];
        }
        int kd = tap / 9, r9 = tap - kd * 9, kh2 = r9 / 3, kw2 = r9 - kh2 * 3;
        int rd = ((d + kd - 1) >> 1) + 1;
        int rh = ((h + kh2 - 1) >> 1) + 1;
        int rw = ((vox + kw2 - 1) >> 1) + 1;
        int cell = (rd * 18 + rh) * 18 + rw;
        int4 bx = *(const int4*)(xtb + cell * 128 + kh * 64 + quad * 16);
        half8 bfrag = __builtin_bit_cast(half8, bx);
        const _Float16* abh = abuf + (tap & 1) * 6144;
#pragma unroll
        for (int mt = 0; mt < 6; mt++) {
            half8 af = *(const half8*)(abh + fb + mt * 128);
            acc[mt] = __builtin_amdgcn_mfma_f32_16x16x32_f16(af, bfrag, acc[mt], 0, 0, 0);
        }
        __syncthreads();
    }

    // kh reduce through LDS (abuf is free after loop-end barrier)
    float* red = (float*)abuf;                   // [(nsub*96+m)*17 + col], 13 KB
    if (kh == 1) {
#pragma unroll
        for (int mt = 0; mt < 6; mt++)
#pragma unroll
            for (int r = 0; r < 4; r++)
                red[(nsub * 96 + mt * 16 + quad * 4 + r) * 17 + col] = acc[mt][r];
    }
    __syncthreads();
    if (kh == 0) {
#pragma unroll
        for (int mt = 0; mt < 6; mt++)
#pragma unroll
            for (int r = 0; r < 4; r++) {
                int m = mt * 16 + quad * 4 + r;
                if (m < 81) {
                    float v = acc[mt][r] + red[(nsub * 96 + m) * 17 + col] + b_off[m];
                    Pw[m * NVOX + pbase + nsub * 16 + col] = (_Float16)v;
                }
            }
    }
}

// ---------------------------------------------------------------------------
// Kernel B: deformable sample + GEMM + BN stats. Register-direct gather with
// FORCED ILP: all 16 corner loads + 4 A-frag loads issued into named regs
// before consumption; next-tap offsets prefetched under the FMA chain.
// 2048 blocks x 16 vox; 4 waves split taps {7,7,7,6}; 3-way LDS reduce.
// ---------------------------------------------------------------------------
#define ACC8(glo, ghi, Wx) do { \
    s00 += (Wx) * u2h2((unsigned)glo.x); s01 += (Wx) * u2h2((unsigned)glo.y); \
    s02 += (Wx) * u2h2((unsigned)glo.z); s03 += (Wx) * u2h2((unsigned)glo.w); \
    s10 += (Wx) * u2h2((unsigned)ghi.x); s11 += (Wx) * u2h2((unsigned)ghi.y); \
    s12 += (Wx) * u2h2((unsigned)ghi.z); s13 += (Wx) * u2h2((unsigned)ghi.w); \
} while (0)

__global__ __launch_bounds__(256, 4) void deform_kernel(
        const float* __restrict__ bias, float* ws, float* __restrict__ out) {
    __shared__ float pbuf[3][2][16][17];         // partials of waves 1..3, 6.5 KB
    __shared__ float rsum[COUT], rsq[COUT];
    int tid = threadIdx.x, wave = tid >> 6, lane = tid & 63;
    int col = lane & 15, quad = lane >> 4;
    int pbase = blockIdx.x * 16;
    int d = pbase >> 10, h = (pbase >> 5) & 31, w0 = pbase & 31;
    int wcoord = w0 + col;
    int gvox = pbase + col;
    const char* xtb = (const char*)(ws + WS_XT);
    const half8* wa8 = (const half8*)(ws + WS_WA);
    const _Float16* P = (const _Float16*)(ws + WS_P);
    float* gstat = ws + WS_STAT;

    if (tid < COUT) { rsum[tid] = 0.f; rsq[tid] = 0.f; }

    floatx4 acc0 = {0.f, 0.f, 0.f, 0.f}, acc1 = {0.f, 0.f, 0.f, 0.f};
    int tbeg = wave * 7, tend = min(27, wave * 7 + 7);
    int sub = quad * 16;                         // byte offset of channel slice

    // prefetch first tap's offsets
    float od = (float)P[(3 * tbeg + 0) * NVOX + gvox];
    float oh = (float)P[(3 * tbeg + 1) * NVOX + gvox];
    float ow = (float)P[(3 * tbeg + 2) * NVOX + gvox];

#pragma unroll 1
    for (int tap = tbeg; tap < tend; tap++) {
        int kd = tap / 9, r9 = tap - kd * 9, kh2 = r9 / 3, kw2 = r9 - kh2 * 3;
        float pdc = (float)(d + kd - 1) + od;
        float phc = (float)(h + kh2 - 1) + oh;
        float pwc = (float)(wcoord + kw2 - 1) + ow;
        float fd0 = floorf(pdc), fh0 = floorf(phc), fw0 = floorf(pwc);
        float fd = pdc - fd0, fh = phc - fh0, fw = pwc - fw0;
        int id = (int)fd0, ih = (int)fh0, iw = (int)fw0;
        // corner bases in BYTES (cell * 128)
        int rd0 = ((min(max(id,     -2), 33) >> 1) + 1) * (324 * 128);
        int rd1 = ((min(max(id + 1, -2), 33) >> 1) + 1) * (324 * 128);
        int rh0 = ((min(max(ih,     -2), 33) >> 1) + 1) * (18 * 128);
        int rh1 = ((min(max(ih + 1, -2), 33) >> 1) + 1) * (18 * 128);
        int rw0 = ((min(max(iw,     -2), 33) >> 1) + 1) * 128;
        int rw1 = ((min(max(iw + 1, -2), 33) >> 1) + 1) * 128;

        // ---- issue ALL gathers into named regs (forces in-flight ILP) ----
        const char* b0 = xtb + (rd0 + rh0 + rw0) + sub;
        const char* b1 = xtb + (rd0 + rh0 + rw1) + sub;
        const char* b2 = xtb + (rd0 + rh1 + rw0) + sub;
        const char* b3 = xtb + (rd0 + rh1 + rw1) + sub;
        const char* b4 = xtb + (rd1 + rh0 + rw0) + sub;
        const char* b5 = xtb + (rd1 + rh0 + rw1) + sub;
        const char* b6 = xtb + (rd1 + rh1 + rw0) + sub;
        const char* b7 = xtb + (rd1 + rh1 + rw1) + sub;
        int4 g0l = *(const int4*)(b0), g0h = *(const int4*)(b0 + 64);
        int4 g1l = *(const int4*)(b1), g1h = *(const int4*)(b1 + 64);
        int4 g2l = *(const int4*)(b2), g2h = *(const int4*)(b2 + 64);
        int4 g3l = *(const int4*)(b3), g3h = *(const int4*)(b3 + 64);
        int4 g4l = *(const int4*)(b4), g4h = *(const int4*)(b4 + 64);
        int4 g5l = *(const int4*)(b5), g5h = *(const int4*)(b5 + 64);
        int4 g6l = *(const int4*)(b6), g6h = *(const int4*)(b6 + 64);
        int4 g7l = *(const int4*)(b7), g7h = *(const int4*)(b7 + 64);

        // A-fragments for this tap (independent; issue while gathers fly)
        int kb = tap * 8 + quad;
        half8 a00 = wa8[kb * 32 + col];
        half8 a01 = wa8[kb * 32 + 16 + col];
        half8 a10 = wa8[(kb + 4) * 32 + col];
        half8 a11 = wa8[(kb + 4) * 32 + 16 + col];

        // prefetch next tap's offsets under the FMA chain
        if (tap + 1 < tend) {
            od = (float)P[(3 * tap + 3) * NVOX + gvox];
            oh = (float)P[(3 * tap + 4) * NVOX + gvox];
            ow = (float)P[(3 * tap + 5) * NVOX + gvox];
        }

        // trilinear weights (VALU, overlaps load latency)
        float gd = 1.f - fd, gh = 1.f - fh, gw = 1.f - fw;
        half2v W0 = u2h2(dup16(gd * gh * gw)), W1 = u2h2(dup16(gd * gh * fw));
        half2v W2 = u2h2(dup16(gd * fh * gw)), W3 = u2h2(dup16(gd * fh * fw));
        half2v W4 = u2h2(dup16(fd * gh * gw)), W5 = u2h2(dup16(fd * gh * fw));
        half2v W6 = u2h2(dup16(fd * fh * gw)), W7 = u2h2(dup16(fd * fh * fw));

        half2v s00 = {0, 0}, s01 = {0, 0}, s02 = {0, 0}, s03 = {0, 0};
        half2v s10 = {0, 0}, s11 = {0, 0}, s12 = {0, 0}, s13 = {0, 0};
        ACC8(g0l, g0h, W0); ACC8(g1l, g1h, W1);
        ACC8(g2l, g2h, W2); ACC8(g3l, g3h, W3);
        ACC8(g4l, g4h, W4); ACC8(g5l, g5h, W5);
        ACC8(g6l, g6h, W6); ACC8(g7l, g7h, W7);
        half8 bf0 = pk8(s00, s01, s02, s03);     // k = tap*64 +  0 + quad*8 ..
        half8 bf1 = pk8(s10, s11, s12, s13);     // k = tap*64 + 32 + quad*8 ..

        acc0 = __builtin_amdgcn_mfma_f32_16x16x32_f16(a00, bf0, acc0, 0, 0, 0);
        acc1 = __builtin_amdgcn_mfma_f32_16x16x32_f16(a01, bf0, acc1, 0, 0, 0);
        acc0 = __builtin_amdgcn_mfma_f32_16x16x32_f16(a10, bf1, acc0, 0, 0, 0);
        acc1 = __builtin_amdgcn_mfma_f32_16x16x32_f16(a11, bf1, acc1, 0, 0, 0);
    }
    __syncthreads();
    if (wave > 0) {
#pragma unroll
        for (int r = 0; r < 4; r++) {
            pbuf[wave - 1][0][quad * 4 + r][col] = acc0[r];
            pbuf[wave - 1][1][quad * 4 + r][col] = acc1[r];
        }
    }
    __syncthreads();
    if (wave == 0) {
#pragma unroll
        for (int r = 0; r < 4; r++) {
            int i = quad * 4 + r;
            int o0 = i;
            float v0 = acc0[r] + pbuf[0][0][i][col] + pbuf[1][0][i][col]
                     + pbuf[2][0][i][col] + bias[o0];
            out[o0 * NVOX + gvox] = v0;
            atomicAdd(&rsum[o0], v0);
            atomicAdd(&rsq[o0], v0 * v0);
            int o1 = 16 + i;
            float v1 = acc1[r] + pbuf[0][1][i][col] + pbuf[1][1][i][col]
                     + pbuf[2][1][i][col] + bias[o1];
            out[o1 * NVOX + gvox] = v1;
            atomicAdd(&rsum[o1], v1);
            atomicAdd(&rsq[o1], v1 * v1);
        }
    }
    __syncthreads();
    if (tid < COUT) {
        atomicAdd(&gstat[tid], rsum[tid]);
        atomicAdd(&gstat[COUT + tid], rsq[tid]);
    }
}

// ---------------------------------------------------------------------------
// BN finalize + ReLU, in-place on d_out (unchanged).
// ---------------------------------------------------------------------------
__global__ void bn_kernel(const float* __restrict__ ws,
                          const float* __restrict__ gamma,
                          const float* __restrict__ beta,
                          float* out) {
    int i = blockIdx.x * 256 + threadIdx.x;
    int o = i >> 15;
    const float* gstat = ws + WS_STAT;
    const float inv = 1.f / 32768.f;
    float mean = gstat[o] * inv;
    float var  = gstat[COUT + o] * inv - mean * mean;
    float sc   = rsqrtf(var + 1e-5f) * gamma[o];
    float v = (out[i] - mean) * sc + beta[o];
    out[i] = fmaxf(v, 0.f);
}

// ---------------------------------------------------------------------------
extern "C" void kernel_launch(void* const* d_in, const int* in_sizes, int n_in,
                              void* d_out, int out_size, void* d_ws, size_t ws_size,
                              hipStream_t stream) {
    const float* x     = (const float*)d_in[0];
    const float* w_off = (const float*)d_in[1];
    const float* b_off = (const float*)d_in[2];
    const float* wmat  = (const float*)d_in[3];
    const float* bias  = (const float*)d_in[4];
    const float* gamma = (const float*)d_in[5];
    const float* beta  = (const float*)d_in[6];
    float* ws  = (float*)d_ws;
    float* out = (float*)d_out;

    prep_all_kernel<<<201, 256, 0, stream>>>(x, w_off, wmat, ws);
    offset_kernel<<<1024, 256, 0, stream>>>(b_off, ws);
    deform_kernel<<<2048, 256, 0, stream>>>(bias, ws, out);
    bn_kernel<<<4096, 256, 0, stream>>>(ws, gamma, beta, out);
}

// Round 3
// 190.211 us; speedup vs baseline: 1.1136x; 1.0083x over previous
//
#include <hip/hip_runtime.h>
#include <math.h>

// Problem constants
#define NVOX  32768     // 32^3 up-res voxels
#define CIN   64
#define COUT  32
#define KT    27
#define CIT   1728      // CIN*KT
#define PSP   5832      // 18^3 padded half-res spatial

// Workspace layout (float offsets)
#define WS_XT   0                 // fp16[5832][64] channel-last padded x
#define WS_WA   186624            // fp16[216][32][8] deform-W A-frags (K tap-major)
#define WS_WO   214272            // fp16[216][96][8] offset-W A-frags (M padded 81->96)
#define WS_STAT 297216            // [32] sum, [32] sumsq
#define WS_P    297280            // fp16[81][32768] offsets (m-major), 5.31 MB

typedef __attribute__((ext_vector_type(8))) _Float16 half8;
typedef __attribute__((ext_vector_type(2))) _Float16 half2v;
typedef __attribute__((ext_vector_type(4))) float floatx4;

static __device__ __forceinline__ unsigned dup16(float w) {
    unsigned short b = __builtin_bit_cast(unsigned short, (_Float16)w);
    return (unsigned)b * 0x10001u;
}
static __device__ __forceinline__ half2v u2h2(unsigned u) {
    return __builtin_bit_cast(half2v, u);
}
static __device__ __forceinline__ half8 pk8(half2v a, half2v b, half2v c, half2v d) {
    union { half8 v; half2v p[4]; } u;
    u.p[0] = a; u.p[1] = b; u.p[2] = c; u.p[3] = d;
    return u.v;
}

// ---------------------------------------------------------------------------
// Merged prep (UNCHANGED — verified):
//   blocks [0,92):    XT fill via LDS transpose
//   blocks [92,119):  pack wmat  -> WA
//   blocks [119,200): pack w_off -> WO
//   block  200:       zero stats
// ---------------------------------------------------------------------------
__global__ __launch_bounds__(256) void prep_all_kernel(
        const float* __restrict__ x, const float* __restrict__ w_off,
        const float* __restrict__ wmat, float* __restrict__ ws) {
    int b = blockIdx.x, t = threadIdx.x;
    if (b < 92) {
        __shared__ _Float16 tile[64][65];
        _Float16* xth = (_Float16*)(ws + WS_XT);
        int tq = t >> 6, lane = t & 63;
        int base = b * 64;
        int cell = base + lane;
        int qw = cell % 18, qh = (cell / 18) % 18, qd = cell / 324;
        bool interior = (cell < PSP) && qd >= 1 && qd <= 16 && qh >= 1 && qh <= 16
                        && qw >= 1 && qw <= 16;
        int xbase = interior ? (((qd - 1) * 16 + (qh - 1)) * 16 + (qw - 1)) : 0;
#pragma unroll
        for (int i = 0; i < 16; i++) {
            int c = tq * 16 + i;
            float v = interior ? x[c * 4096 + xbase] : 0.f;
            tile[lane][c] = (_Float16)v;
        }
        __syncthreads();
#pragma unroll
        for (int i = 0; i < 16; i++) {
            int s = tq * 16 + i;
            int cell2 = base + s;
            if (cell2 < PSP) xth[cell2 * 64 + lane] = tile[s][lane];
        }
    } else if (b < 119) {
        _Float16* wa = (_Float16*)(ws + WS_WA);
        int idx = (b - 92) * 256 + t;           // 0..6911  (kb, o)
        int kb = idx >> 5, o = idx & 31;
        half8 r;
#pragma unroll
        for (int j = 0; j < 8; j++) {
            int kk = kb * 8 + j;                // K index, tap-major
            int tap = kk >> 6, ci = kk & 63;
            r[j] = (_Float16)wmat[o * CIT + ci * 27 + tap];
        }
        *(half8*)(wa + idx * 8) = r;
    } else if (b < 200) {
        _Float16* wo = (_Float16*)(ws + WS_WO);
        int idx = (b - 119) * 256 + t;          // 0..20735 = kb*96 + m
        int kb = idx / 96, m = idx % 96;
        half8 r;
#pragma unroll
        for (int j = 0; j < 8; j++) {
            int kk = kb * 8 + j;
            int tap = kk >> 6, ci = kk & 63;
            float v = (m < 81) ? w_off[(m * 64 + ci) * 27 + tap] : 0.f;
            r[j] = (_Float16)v;
        }
        *(half8*)(wo + idx * 8) = r;
    } else {
        if (t < 64) ws[WS_STAT + t] = 0.f;
    }
}

// ---------------------------------------------------------------------------
// Kernel A: offset GEMM (UNCHANGED). M=96(81), K=1728, N-tile=32.
// ---------------------------------------------------------------------------
__global__ __launch_bounds__(256, 4) void offset_kernel(
        const float* __restrict__ b_off, float* ws) {
    __shared__ __align__(16) _Float16 abuf[2 * 6144];   // 2 x 12288 B
    int tid = threadIdx.x, wave = tid >> 6, lane = tid & 63;
    int nsub = wave & 1, kh = wave >> 1;
    int col = lane & 15, quad = lane >> 4;
    int pbase = blockIdx.x * 32;
    int d = blockIdx.x >> 5, h = blockIdx.x & 31;
    int vox = nsub * 16 + col;                  // w coordinate
    const char* xtb = (const char*)(ws + WS_XT);
    const int4* wsrc = (const int4*)(ws + WS_WO);   // half8 == 16B units
    _Float16* Pw = (_Float16*)(ws + WS_P);
    int4* ab4 = (int4*)abuf;

    // prologue: stage tap 0, preload tap 1 into regs
    int4 ra0 = wsrc[tid], ra1 = wsrc[256 + tid], ra2 = wsrc[512 + tid];
    ab4[tid] = ra0; ab4[256 + tid] = ra1; ab4[512 + tid] = ra2;
    ra0 = wsrc[768 + tid]; ra1 = wsrc[768 + 256 + tid]; ra2 = wsrc[768 + 512 + tid];
    __syncthreads();

    floatx4 acc[6];
#pragma unroll
    for (int mt = 0; mt < 6; mt++) acc[mt] = (floatx4){0.f, 0.f, 0.f, 0.f};

    int fb = (kh * 4 + quad) * 768 + col * 8;   // half-offset of this lane's frags

#pragma unroll 1
    for (int tap = 0; tap < 27; tap++) {
        if (tap < 26) {                          // write tap+1 into other buffer
            int4* dst = ab4 + ((tap + 1) & 1) * 768;
            dst[tid] = ra0; dst[256 + tid] = ra1; dst[512 + tid] = ra2;
        }
        if (tap < 25) {                          // preload tap+2
            const int4* s = wsrc + (tap + 2) * 768;
            ra0 = s[tid]; ra1 = s[256 + tid]; ra2 = s[512 + tid];
        }
        int kd = tap / 9, r9 = tap - kd * 9, kh2 = r9 / 3, kw2 = r9 - kh2 * 3;
        int rd = ((d + kd - 1) >> 1) + 1;
        int rh = ((h + kh2 - 1) >> 1) + 1;
        int rw = ((vox + kw2 - 1) >> 1) + 1;
        int cell = (rd * 18 + rh) * 18 + rw;
        int4 bx = *(const int4*)(xtb + cell * 128 + kh * 64 + quad * 16);
        half8 bfrag = __builtin_bit_cast(half8, bx);
        const _Float16* abh = abuf + (tap & 1) * 6144;
#pragma unroll
        for (int mt = 0; mt < 6; mt++) {
            half8 af = *(const half8*)(abh + fb + mt * 128);
            acc[mt] = __builtin_amdgcn_mfma_f32_16x16x32_f16(af, bfrag, acc[mt], 0, 0, 0);
        }
        __syncthreads();
    }

    // kh reduce through LDS (abuf is free after loop-end barrier)
    float* red = (float*)abuf;                   // [(nsub*96+m)*17 + col], 13 KB
    if (kh == 1) {
#pragma unroll
        for (int mt = 0; mt < 6; mt++)
#pragma unroll
            for (int r = 0; r < 4; r++)
                red[(nsub * 96 + mt * 16 + quad * 4 + r) * 17 + col] = acc[mt][r];
    }
    __syncthreads();
    if (kh == 0) {
#pragma unroll
        for (int mt = 0; mt < 6; mt++)
#pragma unroll
            for (int r = 0; r < 4; r++) {
                int m = mt * 16 + quad * 4 + r;
                if (m < 81) {
                    float v = acc[mt][r] + red[(nsub * 96 + m) * 17 + col] + b_off[m];
                    Pw[m * NVOX + pbase + nsub * 16 + col] = (_Float16)v;
                }
            }
    }
}

// ---------------------------------------------------------------------------
// Kernel B: deformable sample + GEMM + BN stats.
// Round-3 change: ALL per-tap loads (16 gathers + 4 A-frags + 3 next-P) are
// issued in one region terminated by sched_barrier(0), forcing regalloc to
// keep them live (in flight) instead of re-serializing them into ~4 regs.
// __launch_bounds__(256,3) raises the VGPR cap to 168 to make that feasible.
// ---------------------------------------------------------------------------
#define ACC8(glo, ghi, Wx) do { \
    s00 += (Wx) * u2h2((unsigned)glo.x); s01 += (Wx) * u2h2((unsigned)glo.y); \
    s02 += (Wx) * u2h2((unsigned)glo.z); s03 += (Wx) * u2h2((unsigned)glo.w); \
    s10 += (Wx) * u2h2((unsigned)ghi.x); s11 += (Wx) * u2h2((unsigned)ghi.y); \
    s12 += (Wx) * u2h2((unsigned)ghi.z); s13 += (Wx) * u2h2((unsigned)ghi.w); \
} while (0)

__global__ __launch_bounds__(256, 3) void deform_kernel(
        const float* __restrict__ bias, float* ws, float* __restrict__ out) {
    __shared__ float pbuf[3][2][16][17];         // partials of waves 1..3, 6.5 KB
    __shared__ float rsum[COUT], rsq[COUT];
    int tid = threadIdx.x, wave = tid >> 6, lane = tid & 63;
    int col = lane & 15, quad = lane >> 4;
    int pbase = blockIdx.x * 16;
    int d = pbase >> 10, h = (pbase >> 5) & 31, w0 = pbase & 31;
    int wcoord = w0 + col;
    int gvox = pbase + col;
    const char* xtb = (const char*)(ws + WS_XT);
    const half8* wa8 = (const half8*)(ws + WS_WA);
    const _Float16* P = (const _Float16*)(ws + WS_P);
    float* gstat = ws + WS_STAT;

    if (tid < COUT) { rsum[tid] = 0.f; rsq[tid] = 0.f; }

    floatx4 acc0 = {0.f, 0.f, 0.f, 0.f}, acc1 = {0.f, 0.f, 0.f, 0.f};
    int tbeg = wave * 7, tend = min(27, wave * 7 + 7);
    int sub = quad * 16;                         // byte offset of channel slice

    // prefetch first tap's offsets
    float od = (float)P[(3 * tbeg + 0) * NVOX + gvox];
    float oh = (float)P[(3 * tbeg + 1) * NVOX + gvox];
    float ow = (float)P[(3 * tbeg + 2) * NVOX + gvox];

#pragma unroll 1
    for (int tap = tbeg; tap < tend; tap++) {
        int kd = tap / 9, r9 = tap - kd * 9, kh2 = r9 / 3, kw2 = r9 - kh2 * 3;
        float pdc = (float)(d + kd - 1) + od;
        float phc = (float)(h + kh2 - 1) + oh;
        float pwc = (float)(wcoord + kw2 - 1) + ow;
        float fd0 = floorf(pdc), fh0 = floorf(phc), fw0 = floorf(pwc);
        float fd = pdc - fd0, fh = phc - fh0, fw = pwc - fw0;
        int id = (int)fd0, ih = (int)fh0, iw = (int)fw0;
        // corner bases in BYTES (cell * 128)
        int rd0 = ((min(max(id,     -2), 33) >> 1) + 1) * (324 * 128);
        int rd1 = ((min(max(id + 1, -2), 33) >> 1) + 1) * (324 * 128);
        int rh0 = ((min(max(ih,     -2), 33) >> 1) + 1) * (18 * 128);
        int rh1 = ((min(max(ih + 1, -2), 33) >> 1) + 1) * (18 * 128);
        int rw0 = ((min(max(iw,     -2), 33) >> 1) + 1) * 128;
        int rw1 = ((min(max(iw + 1, -2), 33) >> 1) + 1) * 128;

        // ============== LOAD-ISSUE REGION (kept atomic by fence) ==========
        const char* b0 = xtb + (rd0 + rh0 + rw0) + sub;
        const char* b1 = xtb + (rd0 + rh0 + rw1) + sub;
        const char* b2 = xtb + (rd0 + rh1 + rw0) + sub;
        const char* b3 = xtb + (rd0 + rh1 + rw1) + sub;
        const char* b4 = xtb + (rd1 + rh0 + rw0) + sub;
        const char* b5 = xtb + (rd1 + rh0 + rw1) + sub;
        const char* b6 = xtb + (rd1 + rh1 + rw0) + sub;
        const char* b7 = xtb + (rd1 + rh1 + rw1) + sub;
        int4 g0l = *(const int4*)(b0), g0h = *(const int4*)(b0 + 64);
        int4 g1l = *(const int4*)(b1), g1h = *(const int4*)(b1 + 64);
        int4 g2l = *(const int4*)(b2), g2h = *(const int4*)(b2 + 64);
        int4 g3l = *(const int4*)(b3), g3h = *(const int4*)(b3 + 64);
        int4 g4l = *(const int4*)(b4), g4h = *(const int4*)(b4 + 64);
        int4 g5l = *(const int4*)(b5), g5h = *(const int4*)(b5 + 64);
        int4 g6l = *(const int4*)(b6), g6h = *(const int4*)(b6 + 64);
        int4 g7l = *(const int4*)(b7), g7h = *(const int4*)(b7 + 64);

        // A-fragments for this tap (independent; fly with the gathers)
        int kb = tap * 8 + quad;
        half8 a00 = wa8[kb * 32 + col];
        half8 a01 = wa8[kb * 32 + 16 + col];
        half8 a10 = wa8[(kb + 4) * 32 + col];
        half8 a11 = wa8[(kb + 4) * 32 + 16 + col];

        // next tap's offsets (consumed next iteration)
        if (tap + 1 < tend) {
            od = (float)P[(3 * tap + 3) * NVOX + gvox];
            oh = (float)P[(3 * tap + 4) * NVOX + gvox];
            ow = (float)P[(3 * tap + 5) * NVOX + gvox];
        }
        __builtin_amdgcn_sched_barrier(0);   // nothing crosses: all loads stay issued
        // ==================================================================

        // trilinear weights (VALU, runs while loads are in flight)
        float gd = 1.f - fd, gh = 1.f - fh, gw = 1.f - fw;
        half2v W0 = u2h2(dup16(gd * gh * gw)), W1 = u2h2(dup16(gd * gh * fw));
        half2v W2 = u2h2(dup16(gd * fh * gw)), W3 = u2h2(dup16(gd * fh * fw));
        half2v W4 = u2h2(dup16(fd * gh * gw)), W5 = u2h2(dup16(fd * gh * fw));
        half2v W6 = u2h2(dup16(fd * fh * gw)), W7 = u2h2(dup16(fd * fh * fw));

        half2v s00 = {0, 0}, s01 = {0, 0}, s02 = {0, 0}, s03 = {0, 0};
        half2v s10 = {0, 0}, s11 = {0, 0}, s12 = {0, 0}, s13 = {0, 0};
        ACC8(g0l, g0h, W0); ACC8(g1l, g1h, W1);
        ACC8(g2l, g2h, W2); ACC8(g3l, g3h, W3);
        ACC8(g4l, g4h, W4); ACC8(g5l, g5h, W5);
        ACC8(g6l, g6h, W6); ACC8(g7l, g7h, W7);
        half8 bf0 = pk8(s00, s01, s02, s03);     // k = tap*64 +  0 + quad*8 ..
        half8 bf1 = pk8(s10, s11, s12, s13);     // k = tap*64 + 32 + quad*8 ..

        acc0 = __builtin_amdgcn_mfma_f32_16x16x32_f16(a00, bf0, acc0, 0, 0, 0);
        acc1 = __builtin_amdgcn_mfma_f32_16x16x32_f16(a01, bf0, acc1, 0, 0, 0);
        acc0 = __builtin_amdgcn_mfma_f32_16x16x32_f16(a10, bf1, acc0, 0, 0, 0);
        acc1 = __builtin_amdgcn_mfma_f32_16x16x32_f16(a11, bf1, acc1, 0, 0, 0);
    }
    __syncthreads();
    if (wave > 0) {
#pragma unroll
        for (int r = 0; r < 4; r++) {
            pbuf[wave - 1][0][quad * 4 + r][col] = acc0[r];
            pbuf[wave - 1][1][quad * 4 + r][col] = acc1[r];
        }
    }
    __syncthreads();
    if (wave == 0) {
#pragma unroll
        for (int r = 0; r < 4; r++) {
            int i = quad * 4 + r;
            int o0 = i;
            float v0 = acc0[r] + pbuf[0][0][i][col] + pbuf[1][0][i][col]
                     + pbuf[2][0][i][col] + bias[o0];
            out[o0 * NVOX + gvox] = v0;
            atomicAdd(&rsum[o0], v0);
            atomicAdd(&rsq[o0], v0 * v0);
            int o1 = 16 + i;
            float v1 = acc1[r] + pbuf[0][1][i][col] + pbuf[1][1][i][col]
                     + pbuf[2][1][i][col] + bias[o1];
            out[o1 * NVOX + gvox] = v1;
            atomicAdd(&rsum[o1], v1);
            atomicAdd(&rsq[o1], v1 * v1);
        }
    }
    __syncthreads();
    if (tid < COUT) {
        atomicAdd(&gstat[tid], rsum[tid]);
        atomicAdd(&gstat[COUT + tid], rsq[tid]);
    }
}

// ---------------------------------------------------------------------------
// BN finalize + ReLU, in-place on d_out (unchanged).
// ---------------------------------------------------------------------------
__global__ void bn_kernel(const float* __restrict__ ws,
                          const float* __restrict__ gamma,
                          const float* __restrict__ beta,
                          float* out) {
    int i = blockIdx.x * 256 + threadIdx.x;
    int o = i >> 15;
    const float* gstat = ws + WS_STAT;
    const float inv = 1.f / 32768.f;
    float mean = gstat[o] * inv;
    float var  = gstat[COUT + o] * inv - mean * mean;
    float sc   = rsqrtf(var + 1e-5f) * gamma[o];
    float v = (out[i] - mean) * sc + beta[o];
    out[i] = fmaxf(v, 0.f);
}

// ---------------------------------------------------------------------------
extern "C" void kernel_launch(void* const* d_in, const int* in_sizes, int n_in,
                              void* d_out, int out_size, void* d_ws, size_t ws_size,
                              hipStream_t stream) {
    const float* x     = (const float*)d_in[0];
    const float* w_off = (const float*)d_in[1];
    const float* b_off = (const float*)d_in[2];
    const float* wmat  = (const float*)d_in[3];
    const float* bias  = (const float*)d_in[4];
    const float* gamma = (const float*)d_in[5];
    const float* beta  = (const float*)d_in[6];
    float* ws  = (float*)d_ws;
    float* out = (float*)d_out;

    prep_all_kernel<<<201, 256, 0, stream>>>(x, w_off, wmat, ws);
    offset_kernel<<<1024, 256, 0, stream>>>(b_off, ws);
    deform_kernel<<<2048, 256, 0, stream>>>(bias, ws, out);
    bn_kernel<<<4096, 256, 0, stream>>>(ws, gamma, beta, out);
}

// Round 4
// 146.336 us; speedup vs baseline: 1.4475x; 1.2998x over previous
//
#include <hip/hip_runtime.h>
#include <math.h>

// Problem constants
#define NVOX  32768     // 32^3 up-res voxels
#define CIN   64
#define COUT  32
#define KT    27
#define CIT   1728      // CIN*KT
#define PSP   5832      // 18^3 padded half-res spatial

// Workspace layout (float offsets)
#define WS_XT   0                 // fp16[5832][64] channel-last padded x
#define WS_WA   186624            // fp16[216][32][8] deform-W A-frags (K tap-major)
#define WS_WO   214272            // fp16[216][96][8] offset-W A-frags (M padded 81->96)
#define WS_STAT 297216            // [32] sum, [32] sumsq
#define WS_P    297280            // fp16[81][32768] offsets (m-major), 5.31 MB

typedef __attribute__((ext_vector_type(8))) _Float16 half8;
typedef __attribute__((ext_vector_type(2))) _Float16 half2v;
typedef __attribute__((ext_vector_type(4))) float floatx4;

static __device__ __forceinline__ unsigned dup16(float w) {
    unsigned short b = __builtin_bit_cast(unsigned short, (_Float16)w);
    return (unsigned)b * 0x10001u;
}
static __device__ __forceinline__ half2v u2h2(unsigned u) {
    return __builtin_bit_cast(half2v, u);
}
static __device__ __forceinline__ half8 pk8(half2v a, half2v b, half2v c, half2v d) {
    union { half8 v; half2v p[4]; } u;
    u.p[0] = a; u.p[1] = b; u.p[2] = c; u.p[3] = d;
    return u.v;
}

// ---------------------------------------------------------------------------
// Merged prep (UNCHANGED — verified):
//   blocks [0,92):    XT fill via LDS transpose
//   blocks [92,119):  pack wmat  -> WA
//   blocks [119,200): pack w_off -> WO
//   block  200:       zero stats
// ---------------------------------------------------------------------------
__global__ __launch_bounds__(256) void prep_all_kernel(
        const float* __restrict__ x, const float* __restrict__ w_off,
        const float* __restrict__ wmat, float* __restrict__ ws) {
    int b = blockIdx.x, t = threadIdx.x;
    if (b < 92) {
        __shared__ _Float16 tile[64][65];
        _Float16* xth = (_Float16*)(ws + WS_XT);
        int tq = t >> 6, lane = t & 63;
        int base = b * 64;
        int cell = base + lane;
        int qw = cell % 18, qh = (cell / 18) % 18, qd = cell / 324;
        bool interior = (cell < PSP) && qd >= 1 && qd <= 16 && qh >= 1 && qh <= 16
                        && qw >= 1 && qw <= 16;
        int xbase = interior ? (((qd - 1) * 16 + (qh - 1)) * 16 + (qw - 1)) : 0;
#pragma unroll
        for (int i = 0; i < 16; i++) {
            int c = tq * 16 + i;
            float v = interior ? x[c * 4096 + xbase] : 0.f;
            tile[lane][c] = (_Float16)v;
        }
        __syncthreads();
#pragma unroll
        for (int i = 0; i < 16; i++) {
            int s = tq * 16 + i;
            int cell2 = base + s;
            if (cell2 < PSP) xth[cell2 * 64 + lane] = tile[s][lane];
        }
    } else if (b < 119) {
        _Float16* wa = (_Float16*)(ws + WS_WA);
        int idx = (b - 92) * 256 + t;           // 0..6911  (kb, o)
        int kb = idx >> 5, o = idx & 31;
        half8 r;
#pragma unroll
        for (int j = 0; j < 8; j++) {
            int kk = kb * 8 + j;                // K index, tap-major
            int tap = kk >> 6, ci = kk & 63;
            r[j] = (_Float16)wmat[o * CIT + ci * 27 + tap];
        }
        *(half8*)(wa + idx * 8) = r;
    } else if (b < 200) {
        _Float16* wo = (_Float16*)(ws + WS_WO);
        int idx = (b - 119) * 256 + t;          // 0..20735 = kb*96 + m
        int kb = idx / 96, m = idx % 96;
        half8 r;
#pragma unroll
        for (int j = 0; j < 8; j++) {
            int kk = kb * 8 + j;
            int tap = kk >> 6, ci = kk & 63;
            float v = (m < 81) ? w_off[(m * 64 + ci) * 27 + tap] : 0.f;
            r[j] = (_Float16)v;
        }
        *(half8*)(wo + idx * 8) = r;
    } else {
        if (t < 64) ws[WS_STAT + t] = 0.f;
    }
}

// ---------------------------------------------------------------------------
// Kernel A: offset GEMM (UNCHANGED). M=96(81), K=1728, N-tile=32.
// ---------------------------------------------------------------------------
__global__ __launch_bounds__(256, 4) void offset_kernel(
        const float* __restrict__ b_off, float* ws) {
    __shared__ __align__(16) _Float16 abuf[2 * 6144];   // 2 x 12288 B
    int tid = threadIdx.x, wave = tid >> 6, lane = tid & 63;
    int nsub = wave & 1, kh = wave >> 1;
    int col = lane & 15, quad = lane >> 4;
    int pbase = blockIdx.x * 32;
    int d = blockIdx.x >> 5, h = blockIdx.x & 31;
    int vox = nsub * 16 + col;                  // w coordinate
    const char* xtb = (const char*)(ws + WS_XT);
    const int4* wsrc = (const int4*)(ws + WS_WO);   // half8 == 16B units
    _Float16* Pw = (_Float16*)(ws + WS_P);
    int4* ab4 = (int4*)abuf;

    // prologue: stage tap 0, preload tap 1 into regs
    int4 ra0 = wsrc[tid], ra1 = wsrc[256 + tid], ra2 = wsrc[512 + tid];
    ab4[tid] = ra0; ab4[256 + tid] = ra1; ab4[512 + tid] = ra2;
    ra0 = wsrc[768 + tid]; ra1 = wsrc[768 + 256 + tid]; ra2 = wsrc[768 + 512 + tid];
    __syncthreads();

    floatx4 acc[6];
#pragma unroll
    for (int mt = 0; mt < 6; mt++) acc[mt] = (floatx4){0.f, 0.f, 0.f, 0.f};

    int fb = (kh * 4 + quad) * 768 + col * 8;   // half-offset of this lane's frags

#pragma unroll 1
    for (int tap = 0; tap < 27; tap++) {
        if (tap < 26) {                          // write tap+1 into other buffer
            int4* dst = ab4 + ((tap + 1) & 1) * 768;
            dst[tid] = ra0; dst[256 + tid] = ra1; dst[512 + tid] = ra2;
        }
        if (tap < 25) {                          // preload tap+2
            const int4* s = wsrc + (tap + 2) * 768;
            ra0 = s[tid]; ra1 = s[256 + tid]; ra2 = s[512 + tid];
        }
        int kd = tap / 9, r9 = tap - kd * 9, kh2 = r9 / 3, kw2 = r9 - kh2 * 3;
        int rd = ((d + kd - 1) >> 1) + 1;
        int rh = ((h + kh2 - 1) >> 1) + 1;
        int rw = ((vox + kw2 - 1) >> 1) + 1;
        int cell = (rd * 18 + rh) * 18 + rw;
        int4 bx = *(const int4*)(xtb + cell * 128 + kh * 64 + quad * 16);
        half8 bfrag = __builtin_bit_cast(half8, bx);
        const _Float16* abh = abuf + (tap & 1) * 6144;
#pragma unroll
        for (int mt = 0; mt < 6; mt++) {
            half8 af = *(const half8*)(abh + fb + mt * 128);
            acc[mt] = __builtin_amdgcn_mfma_f32_16x16x32_f16(af, bfrag, acc[mt], 0, 0, 0);
        }
        __syncthreads();
    }

    // kh reduce through LDS (abuf is free after loop-end barrier)
    float* red = (float*)abuf;                   // [(nsub*96+m)*17 + col], 13 KB
    if (kh == 1) {
#pragma unroll
        for (int mt = 0; mt < 6; mt++)
#pragma unroll
            for (int r = 0; r < 4; r++)
                red[(nsub * 96 + mt * 16 + quad * 4 + r) * 17 + col] = acc[mt][r];
    }
    __syncthreads();
    if (kh == 0) {
#pragma unroll
        for (int mt = 0; mt < 6; mt++)
#pragma unroll
            for (int r = 0; r < 4; r++) {
                int m = mt * 16 + quad * 4 + r;
                if (m < 81) {
                    float v = acc[mt][r] + red[(nsub * 96 + m) * 17 + col] + b_off[m];
                    Pw[m * NVOX + pbase + nsub * 16 + col] = (_Float16)v;
                }
            }
    }
}

// ---------------------------------------------------------------------------
// Kernel B (REWRITTEN): LDS-staged deformable sample + GEMM + BN stats.
// Block = 2x2x8 up-res voxels (32). Stage the 5x5x8 half-res cell region
// (25.6 KB, covers |off|<2 = 4.8 sigma) in LDS, XOR-swizzled. Gathers become
// ds_read_b128 (throughput-bound, latency-insensitive). Corner addr+weight
// tables built per (tap,vox) item via per-wave LDS scratch — no barriers in
// the main loop. |off|>=2 handled by exact global-gather fallback (rare).
// Waves: (vhalf, kt tap-half). 1024 blocks = 4/CU single round.
// ---------------------------------------------------------------------------
#define ACCP(xl, xh, Wx) do { \
    s00 += (Wx) * u2h2((unsigned)(xl).x); s01 += (Wx) * u2h2((unsigned)(xl).y); \
    s02 += (Wx) * u2h2((unsigned)(xl).z); s03 += (Wx) * u2h2((unsigned)(xl).w); \
    s10 += (Wx) * u2h2((unsigned)(xh).x); s11 += (Wx) * u2h2((unsigned)(xh).y); \
    s12 += (Wx) * u2h2((unsigned)(xh).z); s13 += (Wx) * u2h2((unsigned)(xh).w); \
} while (0)

// decode one (a_pack, w_pack) = two corners; gather from swizzled LDS region
#define DO2(ap, wp) do { \
    int a0_ = (ap) & 0x7fff, a1_ = (int)((((unsigned)(ap)) >> 16) & 0x7fffu); \
    unsigned wl_ = ((unsigned)(wp) & 0xffffu) * 0x10001u; \
    unsigned wh_ = (((unsigned)(wp)) >> 16) * 0x10001u; \
    int4 x0l_ = *(const int4*)(region + (a0_ ^ subLo)); \
    int4 x0h_ = *(const int4*)(region + (a0_ ^ subHi)); \
    int4 x1l_ = *(const int4*)(region + (a1_ ^ subLo)); \
    int4 x1h_ = *(const int4*)(region + (a1_ ^ subHi)); \
    ACCP(x0l_, x0h_, u2h2(wl_)); ACCP(x1l_, x1h_, u2h2(wh_)); \
} while (0)

// slow-path global corner (exact round-2 semantics)
#define GSLOW(Ax, wf) do { \
    half2v Wq_ = u2h2(dup16(wf)); \
    int4 xl_ = *(const int4*)(xtb + (Ax) + subLo); \
    int4 xh_ = *(const int4*)(xtb + (Ax) + subLo + 64); \
    t00 += Wq_ * u2h2((unsigned)xl_.x); t01 += Wq_ * u2h2((unsigned)xl_.y); \
    t02 += Wq_ * u2h2((unsigned)xl_.z); t03 += Wq_ * u2h2((unsigned)xl_.w); \
    t10 += Wq_ * u2h2((unsigned)xh_.x); t11 += Wq_ * u2h2((unsigned)xh_.y); \
    t12 += Wq_ * u2h2((unsigned)xh_.z); t13 += Wq_ * u2h2((unsigned)xh_.w); \
} while (0)

__global__ __launch_bounds__(256, 4) void deform_kernel(
        const float* __restrict__ bias, float* ws, float* __restrict__ out) {
    __shared__ __align__(16) char region[25600];        // 200 cells x 128B, swizzled
    __shared__ __align__(16) int2 scratch[4][16][4];    // per-wave item tables, 2 KB
    __shared__ float pbuf[2][2][16][17];                // [vh][otile][row][col], 8.5 KB
    __shared__ float rsum[COUT], rsq[COUT];

    int tid = threadIdx.x, wave = tid >> 6, lane = tid & 63;
    int col = lane & 15, quad = lane >> 4;
    int bid = blockIdx.x;
    int d0 = (bid >> 6) << 1, h0 = ((bid >> 2) & 15) << 1, w0 = (bid & 3) << 3;

    const char* xtb = (const char*)(ws + WS_XT);
    const half8* wa8 = (const half8*)(ws + WS_WA);
    const _Float16* P = (const _Float16*)(ws + WS_P);
    float* gstat = ws + WS_STAT;

    if (tid < COUT) { rsum[tid] = 0.f; rsq[tid] = 0.f; }

    int pdlo = (d0 >> 1) - 1, phlo = (h0 >> 1) - 1, pwlo = (w0 >> 1) - 1;

    // ---- stage region: 1600 16B chunks, coalesced, XOR-swizzled dest ----
#pragma unroll 1
    for (int it = 0; it < 7; it++) {
        int i = it * 256 + tid;
        if (i < 1600) {
            int r = i >> 3, c16 = i & 7;
            int rd = r / 40, rem = r - rd * 40, rh = rem >> 3, rw = rem & 7;
            int pd = min(max(pdlo + rd, 0), 17);
            int ph = min(max(phlo + rh, 0), 17);
            int pw = min(max(pwlo + rw, 0), 17);
            int cell = (pd * 18 + ph) * 18 + pw;
            int4 vsrc = *(const int4*)(xtb + cell * 128 + c16 * 16);
            *(int4*)(region + r * 128 + ((c16 * 16) ^ ((r & 7) << 4))) = vsrc;
        }
    }
    __syncthreads();

    // ---- per-wave role ----
    int vh = wave & 1, kt = wave >> 1;
    int v = vh * 16 + col;
    int dv = v >> 4, hv = (v >> 3) & 1, wv = v & 7;
    int dcoord = d0 + dv, hcoord = h0 + hv, wcoord = w0 + wv;
    int gvox = dcoord * 1024 + hcoord * 32 + wcoord;
    int tbeg = kt ? 14 : 0, tend = kt ? 27 : 14;
    int subLo = quad * 16, subHi = subLo + 64;
    int bd = quad >> 1, bh = quad & 1;

    floatx4 acc0 = {0.f, 0.f, 0.f, 0.f}, acc1 = {0.f, 0.f, 0.f, 0.f};

    float od = (float)P[(3 * tbeg + 0) * NVOX + gvox];
    float oh = (float)P[(3 * tbeg + 1) * NVOX + gvox];
    float ow = (float)P[(3 * tbeg + 2) * NVOX + gvox];

#pragma unroll 1
    for (int tap = tbeg; tap < tend; tap++) {
        int kd = tap / 9, r9 = tap - kd * 9, kh2 = r9 / 3, kw2 = r9 - kh2 * 3;
        float pdc = (float)(dcoord + kd - 1) + od;
        float phc = (float)(hcoord + kh2 - 1) + oh;
        float pwc = (float)(wcoord + kw2 - 1) + ow;
        float fd0 = floorf(pdc), fh0 = floorf(phc), fw0 = floorf(pwc);
        float fd = pdc - fd0, fh = phc - fh0, fw = pwc - fw0;
        int id = (int)fd0, ih = (int)fh0, iw = (int)fw0;

        // pad cells for all 6 corner planes
        int cd0 = ((min(max(id,     -2), 33)) >> 1) + 1;
        int cd1 = ((min(max(id + 1, -2), 33)) >> 1) + 1;
        int ch0 = ((min(max(ih,     -2), 33)) >> 1) + 1;
        int ch1 = ((min(max(ih + 1, -2), 33)) >> 1) + 1;
        int cw0 = ((min(max(iw,     -2), 33)) >> 1) + 1;
        int cw1 = ((min(max(iw + 1, -2), 33)) >> 1) + 1;
        int sd0 = cd0 - pdlo, sd1 = cd1 - pdlo;
        int sh0 = ch0 - phlo, sh1 = ch1 - phlo;
        int sw0 = cw0 - pwlo, sw1 = cw1 - pwlo;
        bool oob = ((unsigned)sd0 > 4u) | ((unsigned)sd1 > 4u)
                 | ((unsigned)sh0 > 4u) | ((unsigned)sh1 > 4u)
                 | ((unsigned)sw0 > 7u) | ((unsigned)sw1 > 7u);

        // this lane builds corners (bd,bh,0) and (bd,bh,1)
        int sdq = bd ? sd1 : sd0, shq = bh ? sh1 : sh0;
        int rb = (sdq * 5 + shq) * 8;
        int r0 = rb + sw0, r1 = rb + sw1;
        int a0 = oob ? 0x8000 : ((r0 << 7) | ((r0 & 7) << 4));
        int a1 = oob ? 0x8000 : ((r1 << 7) | ((r1 & 7) << 4));
        float gdw = 1.f - fd, ghw = 1.f - fh, gww = 1.f - fw;
        float wd = bd ? fd : gdw, wh = bh ? fh : ghw;
        float wdh = wd * wh;
        unsigned wb0 = (unsigned)__builtin_bit_cast(unsigned short, (_Float16)(wdh * gww));
        unsigned wb1 = (unsigned)__builtin_bit_cast(unsigned short, (_Float16)(wdh * fw));
        scratch[wave][col][quad] = make_int2(a0 | (a1 << 16), (int)(wb0 | (wb1 << 16)));

        // prefetch next tap's offsets (hides under LDS work)
        if (tap + 1 < tend) {
            od = (float)P[(3 * tap + 3) * NVOX + gvox];
            oh = (float)P[(3 * tap + 4) * NVOX + gvox];
            ow = (float)P[(3 * tap + 5) * NVOX + gvox];
        }

        // A-fragments (global, L1-warm)
        int kb = tap * 8 + quad;
        half8 a00 = wa8[kb * 32 + col];
        half8 a01 = wa8[kb * 32 + 16 + col];
        half8 a10 = wa8[(kb + 4) * 32 + col];
        half8 a11 = wa8[(kb + 4) * 32 + 16 + col];

        // read back this voxel's full 8-corner table (broadcast across quads)
        const int4* sc = (const int4*)&scratch[wave][col][0];
        int4 p0 = sc[0], p1 = sc[1];

        half2v s00 = {0, 0}, s01 = {0, 0}, s02 = {0, 0}, s03 = {0, 0};
        half2v s10 = {0, 0}, s11 = {0, 0}, s12 = {0, 0}, s13 = {0, 0};
        DO2(p0.x, p0.y); DO2(p0.z, p0.w);
        DO2(p1.x, p1.y); DO2(p1.z, p1.w);

        // rare exact fallback for |off| >= 2 (global gather, round-2 path)
        if (__any((p0.x & 0x8000) != 0)) {
            bool flg = (p0.x & 0x8000) != 0;
            int Rd0 = ((min(max(id,     -2), 33) >> 1) + 1) * (324 * 128);
            int Rd1 = ((min(max(id + 1, -2), 33) >> 1) + 1) * (324 * 128);
            int Rh0 = ((min(max(ih,     -2), 33) >> 1) + 1) * (18 * 128);
            int Rh1 = ((min(max(ih + 1, -2), 33) >> 1) + 1) * (18 * 128);
            int Rw0 = ((min(max(iw,     -2), 33) >> 1) + 1) * 128;
            int Rw1 = ((min(max(iw + 1, -2), 33) >> 1) + 1) * 128;
            half2v t00 = {0,0}, t01 = {0,0}, t02 = {0,0}, t03 = {0,0};
            half2v t10 = {0,0}, t11 = {0,0}, t12 = {0,0}, t13 = {0,0};
            GSLOW(Rd0 + Rh0 + Rw0, gdw * ghw * gww);
            GSLOW(Rd0 + Rh0 + Rw1, gdw * ghw * fw);
            GSLOW(Rd0 + Rh1 + Rw0, gdw * fh  * gww);
            GSLOW(Rd0 + Rh1 + Rw1, gdw * fh  * fw);
            GSLOW(Rd1 + Rh0 + Rw0, fd  * ghw * gww);
            GSLOW(Rd1 + Rh0 + Rw1, fd  * ghw * fw);
            GSLOW(Rd1 + Rh1 + Rw0, fd  * fh  * gww);
            GSLOW(Rd1 + Rh1 + Rw1, fd  * fh  * fw);
            s00 = flg ? t00 : s00; s01 = flg ? t01 : s01;
            s02 = flg ? t02 : s02; s03 = flg ? t03 : s03;
            s10 = flg ? t10 : s10; s11 = flg ? t11 : s11;
            s12 = flg ? t12 : s12; s13 = flg ? t13 : s13;
        }

        half8 bf0 = pk8(s00, s01, s02, s03);     // k = tap*64 +  0 + quad*8 ..
        half8 bf1 = pk8(s10, s11, s12, s13);     // k = tap*64 + 32 + quad*8 ..

        acc0 = __builtin_amdgcn_mfma_f32_16x16x32_f16(a00, bf0, acc0, 0, 0, 0);
        acc1 = __builtin_amdgcn_mfma_f32_16x16x32_f16(a01, bf0, acc1, 0, 0, 0);
        acc0 = __builtin_amdgcn_mfma_f32_16x16x32_f16(a10, bf1, acc0, 0, 0, 0);
        acc1 = __builtin_amdgcn_mfma_f32_16x16x32_f16(a11, bf1, acc1, 0, 0, 0);
    }

    // ---- kt-pair reduce + epilogue ----
    __syncthreads();
    if (kt == 1) {
#pragma unroll
        for (int r = 0; r < 4; r++) {
            pbuf[vh][0][quad * 4 + r][col] = acc0[r];
            pbuf[vh][1][quad * 4 + r][col] = acc1[r];
        }
    }
    __syncthreads();
    if (kt == 0) {
#pragma unroll
        for (int r = 0; r < 4; r++) {
            int i = quad * 4 + r;
            int o0 = i;
            float v0 = acc0[r] + pbuf[vh][0][i][col] + bias[o0];
            out[o0 * NVOX + gvox] = v0;
            atomicAdd(&rsum[o0], v0);
            atomicAdd(&rsq[o0], v0 * v0);
            int o1 = 16 + i;
            float v1 = acc1[r] + pbuf[vh][1][i][col] + bias[o1];
            out[o1 * NVOX + gvox] = v1;
            atomicAdd(&rsum[o1], v1);
            atomicAdd(&rsq[o1], v1 * v1);
        }
    }
    __syncthreads();
    if (tid < COUT) {
        atomicAdd(&gstat[tid], rsum[tid]);
        atomicAdd(&gstat[COUT + tid], rsq[tid]);
    }
}

// ---------------------------------------------------------------------------
// BN finalize + ReLU, in-place on d_out (unchanged).
// ---------------------------------------------------------------------------
__global__ void bn_kernel(const float* __restrict__ ws,
                          const float* __restrict__ gamma,
                          const float* __restrict__ beta,
                          float* out) {
    int i = blockIdx.x * 256 + threadIdx.x;
    int o = i >> 15;
    const float* gstat = ws + WS_STAT;
    const float inv = 1.f / 32768.f;
    float mean = gstat[o] * inv;
    float var  = gstat[COUT + o] * inv - mean * mean;
    float sc   = rsqrtf(var + 1e-5f) * gamma[o];
    float v = (out[i] - mean) * sc + beta[o];
    out[i] = fmaxf(v, 0.f);
}

// ---------------------------------------------------------------------------
extern "C" void kernel_launch(void* const* d_in, const int* in_sizes, int n_in,
                              void* d_out, int out_size, void* d_ws, size_t ws_size,
                              hipStream_t stream) {
    const float* x     = (const float*)d_in[0];
    const float* w_off = (const float*)d_in[1];
    const float* b_off = (const float*)d_in[2];
    const float* wmat  = (const float*)d_in[3];
    const float* bias  = (const float*)d_in[4];
    const float* gamma = (const float*)d_in[5];
    const float* beta  = (const float*)d_in[6];
    float* ws  = (float*)d_ws;
    float* out = (float*)d_out;

    prep_all_kernel<<<201, 256, 0, stream>>>(x, w_off, wmat, ws);
    offset_kernel<<<1024, 256, 0, stream>>>(b_off, ws);
    deform_kernel<<<1024, 256, 0, stream>>>(bias, ws, out);
    bn_kernel<<<4096, 256, 0, stream>>>(ws, gamma, beta, out);
}

// Round 5
// 140.360 us; speedup vs baseline: 1.5091x; 1.0426x over previous
//
#include <hip/hip_runtime.h>
#include <math.h>

// Problem constants
#define NVOX  32768     // 32^3 up-res voxels
#define CIN   64
#define COUT  32
#define KT    27
#define CIT   1728      // CIN*KT
#define PSP   5832      // 18^3 padded half-res spatial

// Workspace layout (float offsets)
#define WS_XT   0                 // fp16[5832][64] channel-last padded x
#define WS_WA   186624            // fp16[216][32][8] deform-W A-frags (K tap-major)
#define WS_W2   214272            // fp16[8][64][96][8] parity-collapsed offset-W frags
#define WS_STAT 410880            // [32] sum, [32] sumsq
#define WS_P    410944            // fp16[81][32768] offsets (m-major), 5.31 MB

typedef __attribute__((ext_vector_type(8))) _Float16 half8;
typedef __attribute__((ext_vector_type(2))) _Float16 half2v;
typedef __attribute__((ext_vector_type(4))) float floatx4;

static __device__ __forceinline__ unsigned dup16(float w) {
    unsigned short b = __builtin_bit_cast(unsigned short, (_Float16)w);
    return (unsigned)b * 0x10001u;
}
static __device__ __forceinline__ half2v u2h2(unsigned u) {
    return __builtin_bit_cast(half2v, u);
}
static __device__ __forceinline__ half8 pk8(half2v a, half2v b, half2v c, half2v d) {
    union { half8 v; half2v p[4]; } u;
    u.p[0] = a; u.p[1] = b; u.p[2] = c; u.p[3] = d;
    return u.v;
}

// ---------------------------------------------------------------------------
// Merged prep:
//   blocks [0,92):    XT fill via LDS transpose (unchanged, verified)
//   blocks [92,119):  pack wmat -> WA (unchanged, verified)
//   blocks [119,311): pack parity-collapsed offset weights -> W2
//                     W2[pi][cd,ch,cw][ci] = sum of the 1-8 original taps that
//                     alias to that half-res neighbor cell at parity pi.
//   block  311:       zero stats
// ---------------------------------------------------------------------------
__global__ __launch_bounds__(256) void prep_all_kernel(
        const float* __restrict__ x, const float* __restrict__ w_off,
        const float* __restrict__ wmat, float* __restrict__ ws) {
    int b = blockIdx.x, t = threadIdx.x;
    if (b < 92) {
        __shared__ _Float16 tile[64][65];
        _Float16* xth = (_Float16*)(ws + WS_XT);
        int tq = t >> 6, lane = t & 63;
        int base = b * 64;
        int cell = base + lane;
        int qw = cell % 18, qh = (cell / 18) % 18, qd = cell / 324;
        bool interior = (cell < PSP) && qd >= 1 && qd <= 16 && qh >= 1 && qh <= 16
                        && qw >= 1 && qw <= 16;
        int xbase = interior ? (((qd - 1) * 16 + (qh - 1)) * 16 + (qw - 1)) : 0;
#pragma unroll
        for (int i = 0; i < 16; i++) {
            int c = tq * 16 + i;
            float v = interior ? x[c * 4096 + xbase] : 0.f;
            tile[lane][c] = (_Float16)v;
        }
        __syncthreads();
#pragma unroll
        for (int i = 0; i < 16; i++) {
            int s = tq * 16 + i;
            int cell2 = base + s;
            if (cell2 < PSP) xth[cell2 * 64 + lane] = tile[s][lane];
        }
    } else if (b < 119) {
        _Float16* wa = (_Float16*)(ws + WS_WA);
        int idx = (b - 92) * 256 + t;           // 0..6911  (kb, o)
        int kb = idx >> 5, o = idx & 31;
        half8 r;
#pragma unroll
        for (int j = 0; j < 8; j++) {
            int kk = kb * 8 + j;                // K index, tap-major
            int tap = kk >> 6, ci = kk & 63;
            r[j] = (_Float16)wmat[o * CIT + ci * 27 + tap];
        }
        *(half8*)(wa + idx * 8) = r;
    } else if (b < 311) {
        _Float16* w2 = (_Float16*)(ws + WS_W2);
        int idx = (b - 119) * 256 + t;          // 0..49151 = (pi*64 + kb)*96 + m
        int pi = idx / 6144;
        int rem = idx - pi * 6144;
        int kb = rem / 96, m = rem - (rem / 96) * 96;
        int pid = pi >> 2, pih = (pi >> 1) & 1, piw = pi & 1;
        half8 r;
#pragma unroll
        for (int j = 0; j < 8; j++) {
            int kk = kb * 8 + j;                // K in [0,512)
            int tap2 = kk >> 6, ci = kk & 63;
            int cd = tap2 >> 2, ch = (tap2 >> 1) & 1, cw = tap2 & 1;
            // per-axis (start, count) of original taps aliasing this cell
            int bd = pid ? (cd ? 2 : 0) : cd;
            int nd = pid ? (cd ? 1 : 2) : (cd ? 2 : 1);
            int bh = pih ? (ch ? 2 : 0) : ch;
            int nh = pih ? (ch ? 1 : 2) : (ch ? 2 : 1);
            int bw = piw ? (cw ? 2 : 0) : cw;
            int nw = piw ? (cw ? 1 : 2) : (cw ? 2 : 1);
            float s = 0.f;
            if (m < 81) {
                const float* wp = w_off + (m * 64 + ci) * 27;
                for (int a = 0; a < nd; a++)
                    for (int bb = 0; bb < nh; bb++)
                        for (int c = 0; c < nw; c++)
                            s += wp[(bd + a) * 9 + (bh + bb) * 3 + (bw + c)];
            }
            r[j] = (_Float16)s;
        }
        *(half8*)(w2 + idx * 8) = r;
    } else {
        if (t < 64) ws[WS_STAT + t] = 0.f;
    }
}

// ---------------------------------------------------------------------------
// Kernel A: parity-collapsed offset GEMM. Per block: one parity (pi) and 32
// half-res cells (2 qh rows x 16 qw). M=96(81), K=512 (8 cells x 64 ci).
// All 8 B-frags preloaded to registers; per-tap A chunk (12 KB) LDS
// double-buffered, 1 barrier/tap, full unroll. Writes P at parity-mapped
// voxels (layout [m][gvox] unchanged -> deform untouched).
// ---------------------------------------------------------------------------
__global__ __launch_bounds__(256, 4) void offset_kernel(
        const float* __restrict__ b_off, float* ws) {
    __shared__ __align__(16) _Float16 abuf[2 * 6144];   // 2 x 12288 B
    int tid = threadIdx.x, wave = tid >> 6, lane = tid & 63;
    int nsub = wave & 1, kh = wave >> 1;
    int col = lane & 15, quad = lane >> 4;
    int bid = blockIdx.x;
    int pi = bid >> 7, tile = bid & 127;
    int pid = pi >> 2, pih = (pi >> 1) & 1, piw = pi & 1;
    int qd = tile >> 3, qh = (tile & 7) * 2 + nsub;
    const char* xtb = (const char*)(ws + WS_XT);
    const int4* wsrc = (const int4*)(ws + WS_W2) + pi * 6144;
    _Float16* Pw = (_Float16*)(ws + WS_P);
    int4* ab4 = (int4*)abuf;

    // preload all 8 B-frags (independent loads -> full ILP, none in the loop)
    int4 bx[8];
#pragma unroll
    for (int tap = 0; tap < 8; tap++) {
        int cd = tap >> 2, ch = (tap >> 1) & 1, cw = tap & 1;
        int cell = ((qd + cd + pid) * 18 + (qh + ch + pih)) * 18 + (col + cw + piw);
        bx[tap] = *(const int4*)(xtb + cell * 128 + kh * 64 + quad * 16);
    }

    // prologue: stage tap 0, preload tap 1 into regs
    int4 ra0 = wsrc[tid], ra1 = wsrc[256 + tid], ra2 = wsrc[512 + tid];
    ab4[tid] = ra0; ab4[256 + tid] = ra1; ab4[512 + tid] = ra2;
    ra0 = wsrc[768 + tid]; ra1 = wsrc[768 + 256 + tid]; ra2 = wsrc[768 + 512 + tid];
    __syncthreads();

    floatx4 acc[6];
#pragma unroll
    for (int mt = 0; mt < 6; mt++) acc[mt] = (floatx4){0.f, 0.f, 0.f, 0.f};

    int fb = (kh * 4 + quad) * 768 + col * 8;

#pragma unroll
    for (int tap = 0; tap < 8; tap++) {
        if (tap < 7) {                           // write tap+1 into other buffer
            int4* dst = ab4 + ((tap + 1) & 1) * 768;
            dst[tid] = ra0; dst[256 + tid] = ra1; dst[512 + tid] = ra2;
        }
        if (tap < 6) {                           // preload tap+2
            const int4* s2 = wsrc + (tap + 2) * 768;
            ra0 = s2[tid]; ra1 = s2[256 + tid]; ra2 = s2[512 + tid];
        }
        half8 bfrag = __builtin_bit_cast(half8, bx[tap]);
        const _Float16* abh = abuf + (tap & 1) * 6144;
#pragma unroll
        for (int mt = 0; mt < 6; mt++) {
            half8 af = *(const half8*)(abh + fb + mt * 128);
            acc[mt] = __builtin_amdgcn_mfma_f32_16x16x32_f16(af, bfrag, acc[mt], 0, 0, 0);
        }
        __syncthreads();
    }

    // kh reduce through LDS (abuf free after loop-end barrier)
    float* red = (float*)abuf;                   // [(nsub*96+m)*17 + col], 13 KB
    if (kh == 1) {
#pragma unroll
        for (int mt = 0; mt < 6; mt++)
#pragma unroll
            for (int r = 0; r < 4; r++)
                red[(nsub * 96 + mt * 16 + quad * 4 + r) * 17 + col] = acc[mt][r];
    }
    __syncthreads();
    if (kh == 0) {
        int d = 2 * qd + pid, h = 2 * qh + pih;
        int vbase = (d * 32 + h) * 32 + piw;
#pragma unroll
        for (int mt = 0; mt < 6; mt++)
#pragma unroll
            for (int r = 0; r < 4; r++) {
                int m = mt * 16 + quad * 4 + r;
                if (m < 81) {
                    float v = acc[mt][r] + red[(nsub * 96 + m) * 17 + col] + b_off[m];
                    Pw[m * NVOX + vbase + 2 * col] = (_Float16)v;
                }
            }
    }
}

// ---------------------------------------------------------------------------
// Kernel B: LDS-staged deformable sample + GEMM + BN stats (round-4 verified
// structure). Round-5 changes:
//   * swizzle f(r) = (r ^ (r>>3)) & 7  (h/d-corner pairs no longer share a
//     bank group; write and read sides use the same involution)
//   * scratch padded [16][6] (stride 48B: 4-way -> 2-way)
//   * pbuf/rsum/rsq overlay the dead region buffer -> LDS 28672 B, 5 blk/CU
// ---------------------------------------------------------------------------
#define ACCP(xl, xh, Wx) do { \
    s00 += (Wx) * u2h2((unsigned)(xl).x); s01 += (Wx) * u2h2((unsigned)(xl).y); \
    s02 += (Wx) * u2h2((unsigned)(xl).z); s03 += (Wx) * u2h2((unsigned)(xl).w); \
    s10 += (Wx) * u2h2((unsigned)(xh).x); s11 += (Wx) * u2h2((unsigned)(xh).y); \
    s12 += (Wx) * u2h2((unsigned)(xh).z); s13 += (Wx) * u2h2((unsigned)(xh).w); \
} while (0)

#define DO2(ap, wp) do { \
    int a0_ = (ap) & 0x7fff, a1_ = (int)((((unsigned)(ap)) >> 16) & 0x7fffu); \
    unsigned wl_ = ((unsigned)(wp) & 0xffffu) * 0x10001u; \
    unsigned wh_ = (((unsigned)(wp)) >> 16) * 0x10001u; \
    int4 x0l_ = *(const int4*)(region + (a0_ ^ subLo)); \
    int4 x0h_ = *(const int4*)(region + (a0_ ^ subHi)); \
    int4 x1l_ = *(const int4*)(region + (a1_ ^ subLo)); \
    int4 x1h_ = *(const int4*)(region + (a1_ ^ subHi)); \
    ACCP(x0l_, x0h_, u2h2(wl_)); ACCP(x1l_, x1h_, u2h2(wh_)); \
} while (0)

#define GSLOW(Ax, wf) do { \
    half2v Wq_ = u2h2(dup16(wf)); \
    int4 xl_ = *(const int4*)(xtb + (Ax) + subLo); \
    int4 xh_ = *(const int4*)(xtb + (Ax) + subLo + 64); \
    t00 += Wq_ * u2h2((unsigned)xl_.x); t01 += Wq_ * u2h2((unsigned)xl_.y); \
    t02 += Wq_ * u2h2((unsigned)xl_.z); t03 += Wq_ * u2h2((unsigned)xl_.w); \
    t10 += Wq_ * u2h2((unsigned)xh_.x); t11 += Wq_ * u2h2((unsigned)xh_.y); \
    t12 += Wq_ * u2h2((unsigned)xh_.z); t13 += Wq_ * u2h2((unsigned)xh_.w); \
} while (0)

__global__ __launch_bounds__(256, 5) void deform_kernel(
        const float* __restrict__ bias, float* ws, float* __restrict__ out) {
    __shared__ __align__(16) char region[25600];        // 200 cells x 128B, swizzled
    __shared__ __align__(16) int2 scratch[4][16][6];    // padded stride 48B, 3 KB
    // epilogue overlays (region is dead after the main loop):
    float* pbuf = (float*)region;                        // [2][2][16][17] = 8704 B
    float* rsumS = (float*)(region + 8704);              // [32]
    float* rsqS  = (float*)(region + 8704 + 128);        // [32]

    int tid = threadIdx.x, wave = tid >> 6, lane = tid & 63;
    int col = lane & 15, quad = lane >> 4;
    int bid = blockIdx.x;
    int d0 = (bid >> 6) << 1, h0 = ((bid >> 2) & 15) << 1, w0 = (bid & 3) << 3;

    const char* xtb = (const char*)(ws + WS_XT);
    const half8* wa8 = (const half8*)(ws + WS_WA);
    const _Float16* P = (const _Float16*)(ws + WS_P);
    float* gstat = ws + WS_STAT;

    int pdlo = (d0 >> 1) - 1, phlo = (h0 >> 1) - 1, pwlo = (w0 >> 1) - 1;

    // ---- stage region: 1600 16B chunks, coalesced, XOR-swizzled dest ----
#pragma unroll 1
    for (int it = 0; it < 7; it++) {
        int i = it * 256 + tid;
        if (i < 1600) {
            int r = i >> 3, c16 = i & 7;
            int rd = r / 40, rem = r - rd * 40, rh = rem >> 3, rw = rem & 7;
            int pd = min(max(pdlo + rd, 0), 17);
            int ph = min(max(phlo + rh, 0), 17);
            int pw = min(max(pwlo + rw, 0), 17);
            int cell = (pd * 18 + ph) * 18 + pw;
            int4 vsrc = *(const int4*)(xtb + cell * 128 + c16 * 16);
            int f = (r ^ (r >> 3)) & 7;
            *(int4*)(region + r * 128 + ((c16 ^ f) << 4)) = vsrc;
        }
    }
    __syncthreads();

    // ---- per-wave role ----
    int vh = wave & 1, kt = wave >> 1;
    int v = vh * 16 + col;
    int dv = v >> 4, hv = (v >> 3) & 1, wv = v & 7;
    int dcoord = d0 + dv, hcoord = h0 + hv, wcoord = w0 + wv;
    int gvox = dcoord * 1024 + hcoord * 32 + wcoord;
    int tbeg = kt ? 14 : 0, tend = kt ? 27 : 14;
    int subLo = quad * 16, subHi = subLo + 64;
    int bd = quad >> 1, bh = quad & 1;

    floatx4 acc0 = {0.f, 0.f, 0.f, 0.f}, acc1 = {0.f, 0.f, 0.f, 0.f};

    float od = (float)P[(3 * tbeg + 0) * NVOX + gvox];
    float oh = (float)P[(3 * tbeg + 1) * NVOX + gvox];
    float ow = (float)P[(3 * tbeg + 2) * NVOX + gvox];

#pragma unroll 1
    for (int tap = tbeg; tap < tend; tap++) {
        int kd = tap / 9, r9 = tap - kd * 9, kh2 = r9 / 3, kw2 = r9 - kh2 * 3;
        float pdc = (float)(dcoord + kd - 1) + od;
        float phc = (float)(hcoord + kh2 - 1) + oh;
        float pwc = (float)(wcoord + kw2 - 1) + ow;
        float fd0 = floorf(pdc), fh0 = floorf(phc), fw0 = floorf(pwc);
        float fd = pdc - fd0, fh = phc - fh0, fw = pwc - fw0;
        int id = (int)fd0, ih = (int)fh0, iw = (int)fw0;

        int cd0 = ((min(max(id,     -2), 33)) >> 1) + 1;
        int cd1 = ((min(max(id + 1, -2), 33)) >> 1) + 1;
        int ch0 = ((min(max(ih,     -2), 33)) >> 1) + 1;
        int ch1 = ((min(max(ih + 1, -2), 33)) >> 1) + 1;
        int cw0 = ((min(max(iw,     -2), 33)) >> 1) + 1;
        int cw1 = ((min(max(iw + 1, -2), 33)) >> 1) + 1;
        int sd0 = cd0 - pdlo, sd1 = cd1 - pdlo;
        int sh0 = ch0 - phlo, sh1 = ch1 - phlo;
        int sw0 = cw0 - pwlo, sw1 = cw1 - pwlo;
        bool oob = ((unsigned)sd0 > 4u) | ((unsigned)sd1 > 4u)
                 | ((unsigned)sh0 > 4u) | ((unsigned)sh1 > 4u)
                 | ((unsigned)sw0 > 7u) | ((unsigned)sw1 > 7u);

        // this lane builds corners (bd,bh,0) and (bd,bh,1)
        int sdq = bd ? sd1 : sd0, shq = bh ? sh1 : sh0;
        int rb = (sdq * 5 + shq) * 8;
        int r0 = rb + sw0, r1 = rb + sw1;
        int f0 = (r0 ^ (r0 >> 3)) & 7, f1 = (r1 ^ (r1 >> 3)) & 7;
        int a0 = oob ? 0x8000 : ((r0 << 7) | (f0 << 4));
        int a1 = oob ? 0x8000 : ((r1 << 7) | (f1 << 4));
        float gdw = 1.f - fd, ghw = 1.f - fh, gww = 1.f - fw;
        float wd = bd ? fd : gdw, wh = bh ? fh : ghw;
        float wdh = wd * wh;
        unsigned wb0 = (unsigned)__builtin_bit_cast(unsigned short, (_Float16)(wdh * gww));
        unsigned wb1 = (unsigned)__builtin_bit_cast(unsigned short, (_Float16)(wdh * fw));
        scratch[wave][col][quad] = make_int2(a0 | (a1 << 16), (int)(wb0 | (wb1 << 16)));

        if (tap + 1 < tend) {
            od = (float)P[(3 * tap + 3) * NVOX + gvox];
            oh = (float)P[(3 * tap + 4) * NVOX + gvox];
            ow = (float)P[(3 * tap + 5) * NVOX + gvox];
        }

        int kb = tap * 8 + quad;
        half8 a00 = wa8[kb * 32 + col];
        half8 a01 = wa8[kb * 32 + 16 + col];
        half8 a10 = wa8[(kb + 4) * 32 + col];
        half8 a11 = wa8[(kb + 4) * 32 + 16 + col];

        const int4* sc = (const int4*)&scratch[wave][col][0];
        int4 p0 = sc[0], p1 = sc[1];

        half2v s00 = {0, 0}, s01 = {0, 0}, s02 = {0, 0}, s03 = {0, 0};
        half2v s10 = {0, 0}, s11 = {0, 0}, s12 = {0, 0}, s13 = {0, 0};
        DO2(p0.x, p0.y); DO2(p0.z, p0.w);
        DO2(p1.x, p1.y); DO2(p1.z, p1.w);

        if (__any((p0.x & 0x8000) != 0)) {
            bool flg = (p0.x & 0x8000) != 0;
            int Rd0 = ((min(max(id,     -2), 33) >> 1) + 1) * (324 * 128);
            int Rd1 = ((min(max(id + 1, -2), 33) >> 1) + 1) * (324 * 128);
            int Rh0 = ((min(max(ih,     -2), 33) >> 1) + 1) * (18 * 128);
            int Rh1 = ((min(max(ih + 1, -2), 33) >> 1) + 1) * (18 * 128);
            int Rw0 = ((min(max(iw,     -2), 33) >> 1) + 1) * 128;
            int Rw1 = ((min(max(iw + 1, -2), 33) >> 1) + 1) * 128;
            half2v t00 = {0,0}, t01 = {0,0}, t02 = {0,0}, t03 = {0,0};
            half2v t10 = {0,0}, t11 = {0,0}, t12 = {0,0}, t13 = {0,0};
            GSLOW(Rd0 + Rh0 + Rw0, gdw * ghw * gww);
            GSLOW(Rd0 + Rh0 + Rw1, gdw * ghw * fw);
            GSLOW(Rd0 + Rh1 + Rw0, gdw * fh  * gww);
            GSLOW(Rd0 + Rh1 + Rw1, gdw * fh  * fw);
            GSLOW(Rd1 + Rh0 + Rw0, fd  * ghw * gww);
            GSLOW(Rd1 + Rh0 + Rw1, fd  * ghw * fw);
            GSLOW(Rd1 + Rh1 + Rw0, fd  * fh  * gww);
            GSLOW(Rd1 + Rh1 + Rw1, fd  * fh  * fw);
            s00 = flg ? t00 : s00; s01 = flg ? t01 : s01;
            s02 = flg ? t02 : s02; s03 = flg ? t03 : s03;
            s10 = flg ? t10 : s10; s11 = flg ? t11 : s11;
            s12 = flg ? t12 : s12; s13 = flg ? t13 : s13;
        }

        half8 bf0 = pk8(s00, s01, s02, s03);
        half8 bf1 = pk8(s10, s11, s12, s13);

        acc0 = __builtin_amdgcn_mfma_f32_16x16x32_f16(a00, bf0, acc0, 0, 0, 0);
        acc1 = __builtin_amdgcn_mfma_f32_16x16x32_f16(a01, bf0, acc1, 0, 0, 0);
        acc0 = __builtin_amdgcn_mfma_f32_16x16x32_f16(a10, bf1, acc0, 0, 0, 0);
        acc1 = __builtin_amdgcn_mfma_f32_16x16x32_f16(a11, bf1, acc1, 0, 0, 0);
    }

    // ---- epilogue: region dead -> overlay pbuf/rsum ----
    __syncthreads();
    if (kt == 1) {
#pragma unroll
        for (int r = 0; r < 4; r++) {
            pbuf[((vh * 2 + 0) * 16 + quad * 4 + r) * 17 + col] = acc0[r];
            pbuf[((vh * 2 + 1) * 16 + quad * 4 + r) * 17 + col] = acc1[r];
        }
    }
    if (tid < 64) ((float*)(region + 8704))[tid] = 0.f;   // zero rsum+rsq (wave 0)
    __syncthreads();
    if (kt == 0) {
#pragma unroll
        for (int r = 0; r < 4; r++) {
            int i = quad * 4 + r;
            int o0 = i;
            float v0 = acc0[r] + pbuf[((vh * 2 + 0) * 16 + i) * 17 + col] + bias[o0];
            out[o0 * NVOX + gvox] = v0;
            atomicAdd(&rsumS[o0], v0);
            atomicAdd(&rsqS[o0], v0 * v0);
            int o1 = 16 + i;
            float v1 = acc1[r] + pbuf[((vh * 2 + 1) * 16 + i) * 17 + col] + bias[o1];
            out[o1 * NVOX + gvox] = v1;
            atomicAdd(&rsumS[o1], v1);
            atomicAdd(&rsqS[o1], v1 * v1);
        }
    }
    __syncthreads();
    if (tid < COUT) {
        atomicAdd(&gstat[tid], rsumS[tid]);
        atomicAdd(&gstat[COUT + tid], rsqS[tid]);
    }
}

// ---------------------------------------------------------------------------
// BN finalize + ReLU, in-place on d_out (unchanged).
// ---------------------------------------------------------------------------
__global__ void bn_kernel(const float* __restrict__ ws,
                          const float* __restrict__ gamma,
                          const float* __restrict__ beta,
                          float* out) {
    int i = blockIdx.x * 256 + threadIdx.x;
    int o = i >> 15;
    const float* gstat = ws + WS_STAT;
    const float inv = 1.f / 32768.f;
    float mean = gstat[o] * inv;
    float var  = gstat[COUT + o] * inv - mean * mean;
    float sc   = rsqrtf(var + 1e-5f) * gamma[o];
    float v = (out[i] - mean) * sc + beta[o];
    out[i] = fmaxf(v, 0.f);
}

// ---------------------------------------------------------------------------
extern "C" void kernel_launch(void* const* d_in, const int* in_sizes, int n_in,
                              void* d_out, int out_size, void* d_ws, size_t ws_size,
                              hipStream_t stream) {
    const float* x     = (const float*)d_in[0];
    const float* w_off = (const float*)d_in[1];
    const float* b_off = (const float*)d_in[2];
    const float* wmat  = (const float*)d_in[3];
    const float* bias  = (const float*)d_in[4];
    const float* gamma = (const float*)d_in[5];
    const float* beta  = (const float*)d_in[6];
    float* ws  = (float*)d_ws;
    float* out = (float*)d_out;

    prep_all_kernel<<<312, 256, 0, stream>>>(x, w_off, wmat, ws);
    offset_kernel<<<1024, 256, 0, stream>>>(b_off, ws);
    deform_kernel<<<1024, 256, 0, stream>>>(bias, ws, out);
    bn_kernel<<<4096, 256, 0, stream>>>(ws, gamma, beta, out);
}